// Round 6
// baseline (718.732 us; speedup 1.0000x reference)
//
#include <hip/hip_runtime.h>
#include <stdint.h>

#define DIN   64
#define HDIM  64
#define EIN   16
#define EHID  128     // edge hidden width
#define HH    4096    // HDIM*HDIM
#define TC    8256    // T cols: 8192 (layout s*2048 + o*32 + (k&31)) + 64 bias
#define STEPS 3
#define G8    8       // nodes per fused block
#define LDS_BYTES (G8 * TC * 2)   // 132096

typedef short bf16x8 __attribute__((ext_vector_type(8)));
typedef float f32x4  __attribute__((ext_vector_type(4)));

__device__ __forceinline__ unsigned short f32_to_bf16(float f) {
    union { float f; uint32_t u; } v; v.f = f;
    uint32_t r = v.u + 0x7fffu + ((v.u >> 16) & 1u);   // RNE
    return (unsigned short)(r >> 16);
}
__device__ __forceinline__ float bfu_to_f(unsigned short u) {
    union { uint32_t u; float f; } v; v.u = (uint32_t)u << 16; return v.f;
}

// out[n,o] = relu(n_feat[n,:]@W0[:,o]+b0[o]); writes f32 + bf16 copies
__global__ void k_node_mlp(const float* __restrict__ nf, const float* __restrict__ W0,
                           const float* __restrict__ b0, float* __restrict__ outb,
                           unsigned short* __restrict__ outbf, int n_nodes) {
    __shared__ float w0s[DIN * HDIM];
    int tid = threadIdx.x;
    for (int i = tid; i < DIN * HDIM; i += 256) w0s[i] = W0[i];
    __syncthreads();
    int node = blockIdx.x * 4 + (tid >> 6);
    int o = tid & 63;
    if (node >= n_nodes) return;
    float xr = nf[node * DIN + o];
    float acc = b0[o];
#pragma unroll 8
    for (int i = 0; i < DIN; ++i)
        acc += __shfl(xr, i, 64) * w0s[i * HDIM + o];
    float v = fmaxf(acc, 0.f);
    outb[node * HDIM + o] = v;
    outbf[node * HDIM + o] = f32_to_bf16(v);
}

// h[e,c] = relu(e_feat[e,:]@We1[:,c]+be1[c]) -> bf16 [E][128].
// Tiled: 16 edges/block, We1+ef staged in LDS, one uint4 (8 bf16) store/lane.
__global__ void k_edge_mlp(const float* __restrict__ ef, const float* __restrict__ We1,
                           const float* __restrict__ be1, unsigned short* __restrict__ h, int n_edges) {
    __shared__ float w1s[EIN * EHID];   // 8 KB
    __shared__ float xs[16 * EIN];      // 1 KB
    int t = threadIdx.x;
    int e0 = blockIdx.x * 16;
#pragma unroll
    for (int i = t; i < EIN * EHID; i += 256) w1s[i] = We1[i];
    xs[t] = ef[(size_t)e0 * EIN + t];   // 16 edges x 16 feats, coalesced
    __syncthreads();
    int g = t >> 4, c0 = (t & 15) * 8;
    int edge = e0 + g;
    if (edge >= n_edges) return;
    float acc[8];
#pragma unroll
    for (int j = 0; j < 8; ++j) acc[j] = be1[c0 + j];
#pragma unroll
    for (int i = 0; i < EIN; ++i) {
        float xi = xs[g * EIN + i];
#pragma unroll
        for (int j = 0; j < 8; ++j) acc[j] += xi * w1s[i * EHID + c0 + j];
    }
    uint32_t p0 = f32_to_bf16(fmaxf(acc[0], 0.f)) | ((uint32_t)f32_to_bf16(fmaxf(acc[1], 0.f)) << 16);
    uint32_t p1 = f32_to_bf16(fmaxf(acc[2], 0.f)) | ((uint32_t)f32_to_bf16(fmaxf(acc[3], 0.f)) << 16);
    uint32_t p2 = f32_to_bf16(fmaxf(acc[4], 0.f)) | ((uint32_t)f32_to_bf16(fmaxf(acc[5], 0.f)) << 16);
    uint32_t p3 = f32_to_bf16(fmaxf(acc[6], 0.f)) | ((uint32_t)f32_to_bf16(fmaxf(acc[7], 0.f)) << 16);
    uint4 pk = {p0, p1, p2, p3};
    *(uint4*)(h + (size_t)edge * EHID + c0) = pk;
}

// BmatT[c_mfma][i]: two permutations baked in.
// (1) epilogue packing: mfma-col c, g=c&63 -> memory col m = (c&~63)+4*(g&15)+(g>>4)
// (2) T'' B-fragment layout: m<8192 -> s=m>>11, k=s*32+(m&31), o=(m>>5)&63,
//     value = We2[k*4096 + i*64 + o]; m>=8192 -> be2[i*64+(m-8192)]
__global__ void k_bmat(const float* __restrict__ We2, const float* __restrict__ be2,
                       unsigned short* __restrict__ BmatT) {
    int t = blockIdx.x * 256 + threadIdx.x;
    if (t >= TC * 64) return;
    int c = t >> 6, i = t & 63;
    int g = c & 63;
    int m = (c & ~63) + 4 * (g & 15) + (g >> 4);
    float v;
    if (m < 8192) {
        int k = ((m >> 11) << 5) | (m & 31);
        int o = (m >> 5) & 63;
        v = We2[k * HH + i * 64 + o];
    } else {
        v = be2[i * 64 + (m - 8192)];
    }
    BmatT[t] = f32_to_bf16(v);
}

// ---------- FUSED path: build 8 T-rows in LDS, then per-edge MFMA msg ----------
__global__ __launch_bounds__(512) void k_step(const unsigned short* __restrict__ outbf,
                       const unsigned short* __restrict__ BmatT,
                       const unsigned short* __restrict__ h,
                       const int* __restrict__ offS, const int* __restrict__ permS,
                       float* __restrict__ msg, int n_nodes) {
    extern __shared__ unsigned short lds_T[];   // G8 * TC ushorts = 129 KB
    int wave = threadIdx.x >> 6, lane = threadIdx.x & 63;
    int r = lane & 15, q = lane >> 4;
    int nb = blockIdx.x * G8;
    // ---- phase A: T[g][*] for g=0..7 (MFMA M=16, rows 8..15 waste) ----
    {
        int ga = nb + (r < G8 ? r : G8 - 1);
        if (ga >= n_nodes) ga = n_nodes - 1;
        bf16x8 afr0 = *(const bf16x8*)(outbf + (size_t)ga * 64 + q * 8);
        bf16x8 afr1 = *(const bf16x8*)(outbf + (size_t)ga * 64 + 32 + q * 8);
        for (int gi = wave; gi < TC / 64; gi += 8) {   // 129 col-groups of 64
            int cb = gi * 64;
            f32x4 acc[4] = {};
#pragma unroll
            for (int nt = 0; nt < 4; ++nt) {
                size_t cofs = (size_t)(cb + nt * 16 + r) * 64;
                bf16x8 b0 = *(const bf16x8*)(BmatT + cofs + q * 8);
                bf16x8 b1 = *(const bf16x8*)(BmatT + cofs + 32 + q * 8);
                acc[nt] = __builtin_amdgcn_mfma_f32_16x16x32_bf16(afr0, b0, acc[nt], 0, 0, 0);
                acc[nt] = __builtin_amdgcn_mfma_f32_16x16x32_bf16(afr1, b1, acc[nt], 0, 0, 0);
            }
            if (q < 2) {
#pragma unroll
                for (int rg = 0; rg < 4; ++rg) {
                    int g = q * 4 + rg;                // C/D: row=quad*4+reg -> node g
                    ushort4 pk;
                    pk.x = f32_to_bf16(acc[0][rg]);
                    pk.y = f32_to_bf16(acc[1][rg]);
                    pk.z = f32_to_bf16(acc[2][rg]);
                    pk.w = f32_to_bf16(acc[3][rg]);
                    *(ushort4*)(lds_T + (size_t)g * TC + cb + 4 * r) = pk;
                }
            }
        }
    }
    __syncthreads();
    // ---- phase B: wave w handles node nb+w; R5 k_msg with B-frags from LDS ----
    int n = nb + wave;
    if (n >= n_nodes) return;
    int beg = offS[n], end = offS[n + 1];
    if (beg == end) return;
    const unsigned short* Tb = lds_T + (size_t)wave * TC;
    float bias[4];
#pragma unroll
    for (int nt = 0; nt < 4; ++nt)
        bias[nt] = bfu_to_f(Tb[8192 + nt * 16 + r]);
    for (int j0 = beg; j0 < end; j0 += 16) {
        int jc = j0 + r; if (jc >= end) jc = end - 1;
        int e = permS[jc];
        const unsigned short* he = h + (size_t)e * EHID;
        f32x4 acc[4] = {};
#pragma unroll
        for (int s = 0; s < 4; ++s) {        // K = 128 = 4*32
            bf16x8 afr = *(const bf16x8*)(he + s * 32 + q * 8);
#pragma unroll
            for (int nt = 0; nt < 4; ++nt) {
                bf16x8 bfr = *(const bf16x8*)(Tb + s * 2048 + (nt * 16 + r) * 32 + q * 8);
                acc[nt] = __builtin_amdgcn_mfma_f32_16x16x32_bf16(afr, bfr, acc[nt], 0, 0, 0);
            }
        }
#pragma unroll
        for (int rg = 0; rg < 4; ++rg) {
            int jr = j0 + q * 4 + rg;
            if (jr >= end) continue;
            int er = permS[jr];
#pragma unroll
            for (int nt = 0; nt < 4; ++nt)
                msg[(size_t)er * 64 + nt * 16 + r] = acc[nt][rg] + bias[nt];
        }
    }
}

// ---------- FALLBACK path (R5, validated): k_T -> global T, then k_msg ----------
__global__ void k_T(const unsigned short* __restrict__ outbf, const unsigned short* __restrict__ BmatT,
                    unsigned short* __restrict__ T, int n0, int n1) {
    int wave = threadIdx.x >> 6, lane = threadIdx.x & 63;
    int r = lane & 15, q = lane >> 4;
    int eb = n0 + blockIdx.y * 64;
    int cb = blockIdx.x * 256 + wave * 64;
    f32x4 acc[4][4] = {};
#pragma unroll
    for (int s = 0; s < 2; ++s) {
        bf16x8 afr[4], bfr[4];
#pragma unroll
        for (int mt = 0; mt < 4; ++mt) {
            int e = eb + mt * 16 + r;
            if (e >= n1) e = n1 - 1;
            afr[mt] = *(const bf16x8*)(outbf + (size_t)e * 64 + s * 32 + q * 8);
        }
#pragma unroll
        for (int nt = 0; nt < 4; ++nt) {
            int c = cb + nt * 16 + r;
            if (c >= TC) c = 0;
            bfr[nt] = *(const bf16x8*)(BmatT + (size_t)c * 64 + s * 32 + q * 8);
        }
#pragma unroll
        for (int mt = 0; mt < 4; ++mt)
#pragma unroll
            for (int nt = 0; nt < 4; ++nt)
                acc[mt][nt] = __builtin_amdgcn_mfma_f32_16x16x32_bf16(afr[mt], bfr[nt], acc[mt][nt], 0, 0, 0);
    }
    if (cb >= TC) return;
#pragma unroll
    for (int mt = 0; mt < 4; ++mt)
#pragma unroll
        for (int rg = 0; rg < 4; ++rg) {
            int n = eb + mt * 16 + q * 4 + rg;
            if (n >= n1) continue;
            ushort4 pk;
            pk.x = f32_to_bf16(acc[mt][0][rg]);
            pk.y = f32_to_bf16(acc[mt][1][rg]);
            pk.z = f32_to_bf16(acc[mt][2][rg]);
            pk.w = f32_to_bf16(acc[mt][3][rg]);
            *(ushort4*)(T + (size_t)(n - n0) * TC + cb + 4 * r) = pk;
        }
}

__global__ void k_msg(const unsigned short* __restrict__ h, const unsigned short* __restrict__ T,
                      const int* __restrict__ offS, const int* __restrict__ permS,
                      float* __restrict__ msg, int n0, int n1) {
    int wave = threadIdx.x >> 6, lane = threadIdx.x & 63;
    int n = n0 + blockIdx.x * 4 + wave;
    if (n >= n1) return;
    int beg = offS[n], end = offS[n + 1];
    if (beg == end) return;
    int r = lane & 15, q = lane >> 4;
    const unsigned short* Tb = T + (size_t)(n - n0) * TC;
    float bias[4];
#pragma unroll
    for (int nt = 0; nt < 4; ++nt)
        bias[nt] = bfu_to_f(Tb[8192 + nt * 16 + r]);
    for (int j0 = beg; j0 < end; j0 += 16) {
        int jc = j0 + r; if (jc >= end) jc = end - 1;
        int e = permS[jc];
        const unsigned short* he = h + (size_t)e * EHID;
        f32x4 acc[4] = {};
#pragma unroll
        for (int s = 0; s < 4; ++s) {
            bf16x8 afr = *(const bf16x8*)(he + s * 32 + q * 8);
#pragma unroll
            for (int nt = 0; nt < 4; ++nt) {
                bf16x8 bfr = *(const bf16x8*)(Tb + s * 2048 + (nt * 16 + r) * 32 + q * 8);
                acc[nt] = __builtin_amdgcn_mfma_f32_16x16x32_bf16(afr, bfr, acc[nt], 0, 0, 0);
            }
        }
#pragma unroll
        for (int rg = 0; rg < 4; ++rg) {
            int jr = j0 + q * 4 + rg;
            if (jr >= end) continue;
            int er = permS[jr];
#pragma unroll
            for (int nt = 0; nt < 4; ++nt)
                msg[(size_t)er * 64 + nt * 16 + r] = acc[nt][rg] + bias[nt];
        }
    }
}

// histogram src and dst
__global__ void k_hist(const int* __restrict__ src, const int* __restrict__ dst,
                       int* __restrict__ cntS, int* __restrict__ cntD, int n_edges) {
    int e = blockIdx.x * 256 + threadIdx.x;
    if (e >= n_edges) return;
    atomicAdd(&cntS[src[e]], 1);
    atomicAdd(&cntD[dst[e]], 1);
}

// exclusive prefix sum (one block per array; blockIdx.x: 0=S, 1=D)
__global__ void k_scan(const int* __restrict__ cntS, const int* __restrict__ cntD,
                       int* __restrict__ offS, int* __restrict__ offD,
                       int* __restrict__ curS, int* __restrict__ curD, int n, int total) {
    const int* cnt = blockIdx.x ? cntD : cntS;
    int* off = blockIdx.x ? offD : offS;
    int* cur = blockIdx.x ? curD : curS;
    __shared__ int part[256];
    int tid = threadIdx.x;
    int chunk = (n + 255) / 256;
    int c0 = tid * chunk, c1 = c0 + chunk; if (c1 > n) c1 = n; if (c0 > n) c0 = n;
    int s = 0;
    for (int i = c0; i < c1; ++i) s += cnt[i];
    part[tid] = s;
    __syncthreads();
    for (int st = 1; st < 256; st <<= 1) {
        int v = (tid >= st) ? part[tid - st] : 0;
        __syncthreads();
        part[tid] += v;
        __syncthreads();
    }
    int run = tid ? part[tid - 1] : 0;
    for (int i = c0; i < c1; ++i) { off[i] = run; cur[i] = run; run += cnt[i]; }
    if (tid == 0) off[n] = total;
}

__global__ void k_perm(const int* __restrict__ src, const int* __restrict__ dst,
                       int* __restrict__ curS, int* __restrict__ curD,
                       int* __restrict__ permS, int* __restrict__ permD, int n_edges) {
    int e = blockIdx.x * 256 + threadIdx.x;
    if (e >= n_edges) return;
    permS[atomicAdd(&curS[src[e]], 1)] = e;
    permD[atomicAdd(&curD[dst[e]], 1)] = e;
}

// per dst-node wave: out[d] = relu(sum msg + cbias); atomic-free
__global__ void k_agg(const float* __restrict__ msg, const int* __restrict__ offD,
                      const int* __restrict__ permD, const float* __restrict__ cbias,
                      float* __restrict__ outb, unsigned short* __restrict__ outbf, int n_nodes) {
    int wave = threadIdx.x >> 6, lane = threadIdx.x & 63;
    int d = blockIdx.x * 4 + wave;
    if (d >= n_nodes) return;
    float acc = 0.f;
    int end = offD[d + 1];
    for (int j = offD[d]; j < end; ++j)
        acc += msg[(size_t)permD[j] * 64 + lane];
    float v = fmaxf(acc + cbias[lane], 0.f);
    outb[(size_t)d * 64 + lane] = v;
    outbf[(size_t)d * 64 + lane] = f32_to_bf16(v);
}

// grid MUST be 64 blocks (row stride 256 hardcoded)
__global__ void k_bn_stats(const float* __restrict__ out, float* __restrict__ stat, int n_nodes) {
    __shared__ float s1[256], s2[256];
    int tid = threadIdx.x;
    int f = tid & 63, g = tid >> 6;
    float sum = 0.f, ss = 0.f;
    for (int r = blockIdx.x * 4 + g; r < n_nodes; r += 256) {
        float v = out[r * HDIM + f];
        sum += v; ss += v * v;
    }
    s1[tid] = sum; s2[tid] = ss;
    __syncthreads();
    if (tid < 64) {
        float A = s1[tid] + s1[64 + tid] + s1[128 + tid] + s1[192 + tid];
        float B = s2[tid] + s2[64 + tid] + s2[128 + tid] + s2[192 + tid];
        atomicAdd(&stat[tid], A);
        atomicAdd(&stat[64 + tid], B);
    }
}

__global__ void k_bn_final(const float* __restrict__ stat, const float* __restrict__ gamma,
                           const float* __restrict__ beta, float* __restrict__ sc, int n_nodes) {
    int f = threadIdx.x;
    if (f >= 64) return;
    float mean = stat[f] / n_nodes;
    float var  = stat[64 + f] / n_nodes - mean * mean;   // population var
    float inv  = rsqrtf(var + 1e-5f);
    float scale = gamma[f] * inv;
    sc[f] = scale;
    sc[64 + f] = beta[f] - mean * scale;
}

__global__ void k_bn_apply(const float* __restrict__ out, const float* __restrict__ sc,
                           float* __restrict__ y, int n) {
    int t = blockIdx.x * 256 + threadIdx.x;
    if (t >= n) return;
    int f = t & 63;
    y[t] = out[t] * sc[f] + sc[64 + f];
}

extern "C" void kernel_launch(void* const* d_in, const int* in_sizes, int n_in,
                              void* d_out, int out_size, void* d_ws, size_t ws_size,
                              hipStream_t stream) {
    const float* nf    = (const float*)d_in[0];
    const float* ef    = (const float*)d_in[1];
    const int*   src   = (const int*)d_in[2];
    const int*   dst   = (const int*)d_in[3];
    const float* W0    = (const float*)d_in[4];
    const float* b0    = (const float*)d_in[5];
    const float* We1   = (const float*)d_in[6];
    const float* be1   = (const float*)d_in[7];
    const float* We2   = (const float*)d_in[8];
    const float* be2   = (const float*)d_in[9];
    const float* cbias = (const float*)d_in[10];
    const float* gamma = (const float*)d_in[11];
    const float* beta  = (const float*)d_in[12];
    (void)n_in; (void)out_size;

    int n_nodes = in_sizes[0] / DIN;   // 10000
    int n_edges = in_sizes[2];         // 100000

    char* ws = (char*)d_ws;
    size_t off = 0;
    auto carve = [&](size_t bytes) -> void* {
        void* p = ws + off;
        off = (off + bytes + 255) & ~(size_t)255;
        return p;
    };
    unsigned short* h     = (unsigned short*)carve((size_t)n_edges * EHID * 2);  // 25.6 MB
    float*          msg   = (float*)carve((size_t)n_edges * 64 * 4);             // 25.6 MB
    float*          outb  = (float*)carve((size_t)n_nodes * HDIM * 4);
    unsigned short* outbf = (unsigned short*)carve((size_t)n_nodes * HDIM * 2);
    unsigned short* BmatT = (unsigned short*)carve((size_t)TC * 64 * 2);
    int*            offS  = (int*)carve((size_t)(n_nodes + 1) * 4);
    int*            offD  = (int*)carve((size_t)(n_nodes + 1) * 4);
    int*            curS  = (int*)carve((size_t)n_nodes * 4);
    int*            curD  = (int*)carve((size_t)n_nodes * 4);
    int*            permS = (int*)carve((size_t)n_edges * 4);
    int*            permD = (int*)carve((size_t)n_edges * 4);
    float*          stat  = (float*)carve(128 * 4 + (size_t)2 * n_nodes * 4); // stat + cntS + cntD
    int*            cntS  = (int*)(stat + 128);
    int*            cntD  = cntS + n_nodes;
    float*          sc    = (float*)carve(128 * 4);
    unsigned short* T     = (unsigned short*)(ws + off);   // fallback only
    size_t avail = ws_size > off ? ws_size - off : 0;
    long tcap = (long)(avail / ((size_t)TC * 2));
    if (tcap > n_nodes) tcap = n_nodes;
    if (tcap < 64) tcap = 64;

    // fused path needs a >64KB workgroup LDS allocation — probe support
    bool fused = false;
    if (hipFuncSetAttribute((const void*)k_step, hipFuncAttributeMaxDynamicSharedMemorySize,
                            LDS_BYTES) == hipSuccess) {
        hipFuncAttributes fa;
        if (hipFuncGetAttributes(&fa, (const void*)k_step) == hipSuccess &&
            fa.maxDynamicSharedSizeBytes >= LDS_BYTES)
            fused = true;
    }

    hipMemsetAsync(stat, 0, 128 * 4 + (size_t)2 * n_nodes * 4, stream);

    k_node_mlp<<<dim3((n_nodes + 3) / 4), 256, 0, stream>>>(nf, W0, b0, outb, outbf, n_nodes);
    k_edge_mlp<<<dim3((n_edges + 15) / 16), 256, 0, stream>>>(ef, We1, be1, h, n_edges);
    k_bmat<<<dim3((TC * 64 + 255) / 256), 256, 0, stream>>>(We2, be2, BmatT);
    k_hist<<<dim3((n_edges + 255) / 256), 256, 0, stream>>>(src, dst, cntS, cntD, n_edges);
    k_scan<<<dim3(2), 256, 0, stream>>>(cntS, cntD, offS, offD, curS, curD, n_nodes, n_edges);
    k_perm<<<dim3((n_edges + 255) / 256), 256, 0, stream>>>(src, dst, curS, curD, permS, permD, n_edges);

    for (int step = 0; step < STEPS; ++step) {
        if (fused) {
            k_step<<<dim3((n_nodes + G8 - 1) / G8), 512, LDS_BYTES, stream>>>(
                outbf, BmatT, h, offS, permS, msg, n_nodes);
        } else {
            for (long n0 = 0; n0 < n_nodes; n0 += tcap) {
                long n1 = n0 + tcap; if (n1 > n_nodes) n1 = n_nodes;
                long cnt = n1 - n0;
                k_T<<<dim3((TC + 255) / 256, (cnt + 63) / 64), 256, 0, stream>>>(
                    outbf, BmatT, T, (int)n0, (int)n1);
                k_msg<<<dim3((cnt + 3) / 4), 256, 0, stream>>>(
                    h, T, offS, permS, msg, (int)n0, (int)n1);
            }
        }
        k_agg<<<dim3((n_nodes + 3) / 4), 256, 0, stream>>>(msg, offD, permD, cbias, outb, outbf, n_nodes);
    }

    k_bn_stats<<<dim3(64), 256, 0, stream>>>(outb, stat, n_nodes);
    k_bn_final<<<dim3(1), 64, 0, stream>>>(stat, gamma, beta, sc, n_nodes);
    k_bn_apply<<<dim3((n_nodes * HDIM + 255) / 256), 256, 0, stream>>>(
        outb, sc, (float*)d_out, n_nodes * HDIM);
}

// Round 7
// 512.447 us; speedup vs baseline: 1.4025x; 1.4025x over previous
//
#include <hip/hip_runtime.h>
#include <stdint.h>

#define DIN   64
#define HDIM  64
#define EIN   16
#define EHID  128     // edge hidden width
#define HH    4096    // HDIM*HDIM
#define TC    8256    // T cols: 8192 (layout s*2048 + o*32 + (k&31)) + 64 bias
#define STEPS 3

typedef short bf16x8 __attribute__((ext_vector_type(8)));
typedef float f32x4  __attribute__((ext_vector_type(4)));

__device__ __forceinline__ unsigned short f32_to_bf16(float f) {
    union { float f; uint32_t u; } v; v.f = f;
    uint32_t r = v.u + 0x7fffu + ((v.u >> 16) & 1u);   // RNE
    return (unsigned short)(r >> 16);
}
__device__ __forceinline__ float bfu_to_f(unsigned short u) {
    union { uint32_t u; float f; } v; v.u = (uint32_t)u << 16; return v.f;
}

// out[n,o] = relu(n_feat[n,:]@W0[:,o]+b0[o]); writes f32 + bf16 copies
__global__ void k_node_mlp(const float* __restrict__ nf, const float* __restrict__ W0,
                           const float* __restrict__ b0, float* __restrict__ outb,
                           unsigned short* __restrict__ outbf, int n_nodes) {
    __shared__ float w0s[DIN * HDIM];
    int tid = threadIdx.x;
    for (int i = tid; i < DIN * HDIM; i += 256) w0s[i] = W0[i];
    __syncthreads();
    int node = blockIdx.x * 4 + (tid >> 6);
    int o = tid & 63;
    if (node >= n_nodes) return;
    float xr = nf[node * DIN + o];
    float acc = b0[o];
#pragma unroll 8
    for (int i = 0; i < DIN; ++i)
        acc += __shfl(xr, i, 64) * w0s[i * HDIM + o];
    float v = fmaxf(acc, 0.f);
    outb[node * HDIM + o] = v;
    outbf[node * HDIM + o] = f32_to_bf16(v);
}

// h[e,c] = relu(e_feat[e,:]@We1[:,c]+be1[c]) -> bf16 [E][128].
// Tiled: 16 edges/block, We1+ef staged in LDS, one uint4 (8 bf16) store/lane.
// (validated in R6: absmax bit-identical to scalar version)
__global__ void k_edge_mlp(const float* __restrict__ ef, const float* __restrict__ We1,
                           const float* __restrict__ be1, unsigned short* __restrict__ h, int n_edges) {
    __shared__ float w1s[EIN * EHID];   // 8 KB
    __shared__ float xs[16 * EIN];      // 1 KB
    int t = threadIdx.x;
    int e0 = blockIdx.x * 16;
#pragma unroll
    for (int i = t; i < EIN * EHID; i += 256) w1s[i] = We1[i];
    xs[t] = ef[(size_t)e0 * EIN + t];   // 16 edges x 16 feats, coalesced
    __syncthreads();
    int g = t >> 4, c0 = (t & 15) * 8;
    int edge = e0 + g;
    if (edge >= n_edges) return;
    float acc[8];
#pragma unroll
    for (int j = 0; j < 8; ++j) acc[j] = be1[c0 + j];
#pragma unroll
    for (int i = 0; i < EIN; ++i) {
        float xi = xs[g * EIN + i];
#pragma unroll
        for (int j = 0; j < 8; ++j) acc[j] += xi * w1s[i * EHID + c0 + j];
    }
    uint32_t p0 = f32_to_bf16(fmaxf(acc[0], 0.f)) | ((uint32_t)f32_to_bf16(fmaxf(acc[1], 0.f)) << 16);
    uint32_t p1 = f32_to_bf16(fmaxf(acc[2], 0.f)) | ((uint32_t)f32_to_bf16(fmaxf(acc[3], 0.f)) << 16);
    uint32_t p2 = f32_to_bf16(fmaxf(acc[4], 0.f)) | ((uint32_t)f32_to_bf16(fmaxf(acc[5], 0.f)) << 16);
    uint32_t p3 = f32_to_bf16(fmaxf(acc[6], 0.f)) | ((uint32_t)f32_to_bf16(fmaxf(acc[7], 0.f)) << 16);
    uint4 pk = {p0, p1, p2, p3};
    *(uint4*)(h + (size_t)edge * EHID + c0) = pk;
}

// BmatT[c_mfma][i]: two permutations baked in.
// (1) epilogue packing: mfma-col c, g=c&63 -> memory col m = (c&~63)+4*(g&15)+(g>>4)
// (2) T'' B-fragment layout: m<8192 -> s=m>>11, k=s*32+(m&31), o=(m>>5)&63,
//     value = We2[k*4096 + i*64 + o]; m>=8192 -> be2[i*64+(m-8192)]
__global__ void k_bmat(const float* __restrict__ We2, const float* __restrict__ be2,
                       unsigned short* __restrict__ BmatT) {
    int t = blockIdx.x * 256 + threadIdx.x;
    if (t >= TC * 64) return;
    int c = t >> 6, i = t & 63;
    int g = c & 63;
    int m = (c & ~63) + 4 * (g & 15) + (g >> 4);
    float v;
    if (m < 8192) {
        int k = ((m >> 11) << 5) | (m & 31);
        int o = (m >> 5) & 63;
        v = We2[k * HH + i * 64 + o];
    } else {
        v = be2[i * 64 + (m - 8192)];
    }
    BmatT[t] = f32_to_bf16(v);
}

// T[n, m] = sum_i x[n,i]*B[i,m], bf16 out in T'' layout.
// grid: x = col-tile (dense row writes), y = node-tile.
__global__ void k_T(const unsigned short* __restrict__ outbf, const unsigned short* __restrict__ BmatT,
                    unsigned short* __restrict__ T, int n0, int n1) {
    int wave = threadIdx.x >> 6, lane = threadIdx.x & 63;
    int r = lane & 15, q = lane >> 4;
    int eb = n0 + blockIdx.y * 64;
    int cb = blockIdx.x * 256 + wave * 64;
    f32x4 acc[4][4] = {};
#pragma unroll
    for (int s = 0; s < 2; ++s) {            // K = 64 = 2*32
        bf16x8 afr[4], bfr[4];
#pragma unroll
        for (int mt = 0; mt < 4; ++mt) {
            int e = eb + mt * 16 + r;
            if (e >= n1) e = n1 - 1;
            afr[mt] = *(const bf16x8*)(outbf + (size_t)e * 64 + s * 32 + q * 8);
        }
#pragma unroll
        for (int nt = 0; nt < 4; ++nt) {
            int c = cb + nt * 16 + r;
            if (c >= TC) c = 0;              // clamped load; store guarded
            bfr[nt] = *(const bf16x8*)(BmatT + (size_t)c * 64 + s * 32 + q * 8);
        }
#pragma unroll
        for (int mt = 0; mt < 4; ++mt)
#pragma unroll
            for (int nt = 0; nt < 4; ++nt)
                acc[mt][nt] = __builtin_amdgcn_mfma_f32_16x16x32_bf16(afr[mt], bfr[nt], acc[mt][nt], 0, 0, 0);
    }
    if (cb >= TC) return;
#pragma unroll
    for (int mt = 0; mt < 4; ++mt)
#pragma unroll
        for (int rg = 0; rg < 4; ++rg) {
            int n = eb + mt * 16 + q * 4 + rg;     // C/D: col=lane&15, row=quad*4+reg
            if (n >= n1) continue;
            ushort4 pk;
            pk.x = f32_to_bf16(acc[mt][0][rg]);
            pk.y = f32_to_bf16(acc[mt][1][rg]);
            pk.z = f32_to_bf16(acc[mt][2][rg]);
            pk.w = f32_to_bf16(acc[mt][3][rg]);
            *(ushort4*)(T + (size_t)(n - n0) * TC + cb + 4 * r) = pk;
        }
}

// per src-node wave, MFMA: msg[tile of 16 edges][64 o] = h[edges, 0:128] @ T''[n]
// B-frags: 1-KB coalesced loads from T (L3-resident chunk)
__global__ void k_msg(const unsigned short* __restrict__ h, const unsigned short* __restrict__ T,
                      const int* __restrict__ offS, const int* __restrict__ permS,
                      float* __restrict__ msg, int n0, int n1) {
    int wave = threadIdx.x >> 6, lane = threadIdx.x & 63;
    int n = n0 + blockIdx.x * 4 + wave;
    if (n >= n1) return;
    int beg = offS[n], end = offS[n + 1];
    if (beg == end) return;
    int r = lane & 15, q = lane >> 4;
    const unsigned short* Tb = T + (size_t)(n - n0) * TC;
    float bias[4];
#pragma unroll
    for (int nt = 0; nt < 4; ++nt)
        bias[nt] = bfu_to_f(Tb[8192 + nt * 16 + r]);
    for (int j0 = beg; j0 < end; j0 += 16) {
        int jc = j0 + r; if (jc >= end) jc = end - 1;
        int e = permS[jc];
        const unsigned short* he = h + (size_t)e * EHID;
        f32x4 acc[4] = {};
#pragma unroll
        for (int s = 0; s < 4; ++s) {        // K = 128 = 4*32
            bf16x8 afr = *(const bf16x8*)(he + s * 32 + q * 8);
#pragma unroll
            for (int nt = 0; nt < 4; ++nt) {
                bf16x8 bfr = *(const bf16x8*)(Tb + s * 2048 + (nt * 16 + r) * 32 + q * 8);
                acc[nt] = __builtin_amdgcn_mfma_f32_16x16x32_bf16(afr, bfr, acc[nt], 0, 0, 0);
            }
        }
#pragma unroll
        for (int rg = 0; rg < 4; ++rg) {
            int jr = j0 + q * 4 + rg;
            if (jr >= end) continue;
            int er = permS[jr];
#pragma unroll
            for (int nt = 0; nt < 4; ++nt)
                msg[(size_t)er * 64 + nt * 16 + r] = acc[nt][rg] + bias[nt];
        }
    }
}

// histogram src and dst
__global__ void k_hist(const int* __restrict__ src, const int* __restrict__ dst,
                       int* __restrict__ cntS, int* __restrict__ cntD, int n_edges) {
    int e = blockIdx.x * 256 + threadIdx.x;
    if (e >= n_edges) return;
    atomicAdd(&cntS[src[e]], 1);
    atomicAdd(&cntD[dst[e]], 1);
}

// exclusive prefix sum (one block per array; blockIdx.x: 0=S, 1=D)
__global__ void k_scan(const int* __restrict__ cntS, const int* __restrict__ cntD,
                       int* __restrict__ offS, int* __restrict__ offD,
                       int* __restrict__ curS, int* __restrict__ curD, int n, int total) {
    const int* cnt = blockIdx.x ? cntD : cntS;
    int* off = blockIdx.x ? offD : offS;
    int* cur = blockIdx.x ? curD : curS;
    __shared__ int part[256];
    int tid = threadIdx.x;
    int chunk = (n + 255) / 256;
    int c0 = tid * chunk, c1 = c0 + chunk; if (c1 > n) c1 = n; if (c0 > n) c0 = n;
    int s = 0;
    for (int i = c0; i < c1; ++i) s += cnt[i];
    part[tid] = s;
    __syncthreads();
    for (int st = 1; st < 256; st <<= 1) {
        int v = (tid >= st) ? part[tid - st] : 0;
        __syncthreads();
        part[tid] += v;
        __syncthreads();
    }
    int run = tid ? part[tid - 1] : 0;
    for (int i = c0; i < c1; ++i) { off[i] = run; cur[i] = run; run += cnt[i]; }
    if (tid == 0) off[n] = total;
}

__global__ void k_perm(const int* __restrict__ src, const int* __restrict__ dst,
                       int* __restrict__ curS, int* __restrict__ curD,
                       int* __restrict__ permS, int* __restrict__ permD, int n_edges) {
    int e = blockIdx.x * 256 + threadIdx.x;
    if (e >= n_edges) return;
    permS[atomicAdd(&curS[src[e]], 1)] = e;
    permD[atomicAdd(&curD[dst[e]], 1)] = e;
}

// per dst-node wave: out[d] = relu(sum msg + cbias); atomic-free
__global__ void k_agg(const float* __restrict__ msg, const int* __restrict__ offD,
                      const int* __restrict__ permD, const float* __restrict__ cbias,
                      float* __restrict__ outb, unsigned short* __restrict__ outbf, int n_nodes) {
    int wave = threadIdx.x >> 6, lane = threadIdx.x & 63;
    int d = blockIdx.x * 4 + wave;
    if (d >= n_nodes) return;
    float acc = 0.f;
    int end = offD[d + 1];
    for (int j = offD[d]; j < end; ++j)
        acc += msg[(size_t)permD[j] * 64 + lane];
    float v = fmaxf(acc + cbias[lane], 0.f);
    outb[(size_t)d * 64 + lane] = v;
    outbf[(size_t)d * 64 + lane] = f32_to_bf16(v);
}

// grid MUST be 64 blocks (row stride 256 hardcoded)
__global__ void k_bn_stats(const float* __restrict__ out, float* __restrict__ stat, int n_nodes) {
    __shared__ float s1[256], s2[256];
    int tid = threadIdx.x;
    int f = tid & 63, g = tid >> 6;
    float sum = 0.f, ss = 0.f;
    for (int r = blockIdx.x * 4 + g; r < n_nodes; r += 256) {
        float v = out[r * HDIM + f];
        sum += v; ss += v * v;
    }
    s1[tid] = sum; s2[tid] = ss;
    __syncthreads();
    if (tid < 64) {
        float A = s1[tid] + s1[64 + tid] + s1[128 + tid] + s1[192 + tid];
        float B = s2[tid] + s2[64 + tid] + s2[128 + tid] + s2[192 + tid];
        atomicAdd(&stat[tid], A);
        atomicAdd(&stat[64 + tid], B);
    }
}

__global__ void k_bn_final(const float* __restrict__ stat, const float* __restrict__ gamma,
                           const float* __restrict__ beta, float* __restrict__ sc, int n_nodes) {
    int f = threadIdx.x;
    if (f >= 64) return;
    float mean = stat[f] / n_nodes;
    float var  = stat[64 + f] / n_nodes - mean * mean;   // population var
    float inv  = rsqrtf(var + 1e-5f);
    float scale = gamma[f] * inv;
    sc[f] = scale;
    sc[64 + f] = beta[f] - mean * scale;
}

__global__ void k_bn_apply(const float* __restrict__ out, const float* __restrict__ sc,
                           float* __restrict__ y, int n) {
    int t = blockIdx.x * 256 + threadIdx.x;
    if (t >= n) return;
    int f = t & 63;
    y[t] = out[t] * sc[f] + sc[64 + f];
}

extern "C" void kernel_launch(void* const* d_in, const int* in_sizes, int n_in,
                              void* d_out, int out_size, void* d_ws, size_t ws_size,
                              hipStream_t stream) {
    const float* nf    = (const float*)d_in[0];
    const float* ef    = (const float*)d_in[1];
    const int*   src   = (const int*)d_in[2];
    const int*   dst   = (const int*)d_in[3];
    const float* W0    = (const float*)d_in[4];
    const float* b0    = (const float*)d_in[5];
    const float* We1   = (const float*)d_in[6];
    const float* be1   = (const float*)d_in[7];
    const float* We2   = (const float*)d_in[8];
    const float* be2   = (const float*)d_in[9];
    const float* cbias = (const float*)d_in[10];
    const float* gamma = (const float*)d_in[11];
    const float* beta  = (const float*)d_in[12];
    (void)n_in; (void)out_size;

    int n_nodes = in_sizes[0] / DIN;   // 10000
    int n_edges = in_sizes[2];         // 100000

    char* ws = (char*)d_ws;
    size_t off = 0;
    auto carve = [&](size_t bytes) -> void* {
        void* p = ws + off;
        off = (off + bytes + 255) & ~(size_t)255;
        return p;
    };
    unsigned short* h     = (unsigned short*)carve((size_t)n_edges * EHID * 2);  // 25.6 MB
    float*          msg   = (float*)carve((size_t)n_edges * 64 * 4);             // 25.6 MB
    float*          outb  = (float*)carve((size_t)n_nodes * HDIM * 4);
    unsigned short* outbf = (unsigned short*)carve((size_t)n_nodes * HDIM * 2);
    unsigned short* BmatT = (unsigned short*)carve((size_t)TC * 64 * 2);
    int*            offS  = (int*)carve((size_t)(n_nodes + 1) * 4);
    int*            offD  = (int*)carve((size_t)(n_nodes + 1) * 4);
    int*            curS  = (int*)carve((size_t)n_nodes * 4);
    int*            curD  = (int*)carve((size_t)n_nodes * 4);
    int*            permS = (int*)carve((size_t)n_edges * 4);
    int*            permD = (int*)carve((size_t)n_edges * 4);
    float*          stat  = (float*)carve(128 * 4 + (size_t)2 * n_nodes * 4); // stat + cntS + cntD
    int*            cntS  = (int*)(stat + 128);
    int*            cntD  = cntS + n_nodes;
    float*          sc    = (float*)carve(128 * 4);
    unsigned short* T     = (unsigned short*)(ws + off);
    size_t avail = ws_size > off ? ws_size - off : 0;
    long tcap = (long)(avail / ((size_t)TC * 2));   // ws-capacity bound (node rows)
    if (tcap > n_nodes) tcap = n_nodes;
    if (tcap < 64) tcap = 64;
    // L3-residency bound: T chunk ~83 MB stays in the 256 MB Infinity Cache,
    // so k_msg reads T from L3 (R4 showed a whole 165 MB T leaks to HBM).
    long half = (((long)n_nodes + 1) / 2 + 63) & ~63L;   // 5056 for n=10000
    long tchunk = tcap < half ? tcap : half;

    hipMemsetAsync(stat, 0, 128 * 4 + (size_t)2 * n_nodes * 4, stream);

    k_node_mlp<<<dim3((n_nodes + 3) / 4), 256, 0, stream>>>(nf, W0, b0, outb, outbf, n_nodes);
    k_edge_mlp<<<dim3((n_edges + 15) / 16), 256, 0, stream>>>(ef, We1, be1, h, n_edges);
    k_bmat<<<dim3((TC * 64 + 255) / 256), 256, 0, stream>>>(We2, be2, BmatT);
    k_hist<<<dim3((n_edges + 255) / 256), 256, 0, stream>>>(src, dst, cntS, cntD, n_edges);
    k_scan<<<dim3(2), 256, 0, stream>>>(cntS, cntD, offS, offD, curS, curD, n_nodes, n_edges);
    k_perm<<<dim3((n_edges + 255) / 256), 256, 0, stream>>>(src, dst, curS, curD, permS, permD, n_edges);

    for (int step = 0; step < STEPS; ++step) {
        for (long n0 = 0; n0 < n_nodes; n0 += tchunk) {
            long n1 = n0 + tchunk; if (n1 > n_nodes) n1 = n_nodes;
            long cnt = n1 - n0;
            k_T<<<dim3((TC + 255) / 256, (cnt + 63) / 64), 256, 0, stream>>>(
                outbf, BmatT, T, (int)n0, (int)n1);
            k_msg<<<dim3((cnt + 3) / 4), 256, 0, stream>>>(
                h, T, offS, permS, msg, (int)n0, (int)n1);
        }
        k_agg<<<dim3((n_nodes + 3) / 4), 256, 0, stream>>>(msg, offD, permD, cbias, outb, outbf, n_nodes);
    }

    k_bn_stats<<<dim3(64), 256, 0, stream>>>(outb, stat, n_nodes);
    k_bn_final<<<dim3(1), 64, 0, stream>>>(stat, gamma, beta, sc, n_nodes);
    k_bn_apply<<<dim3((n_nodes * HDIM + 255) / 256), 256, 0, stream>>>(
        outb, sc, (float*)d_out, n_nodes * HDIM);
}

// Round 8
// 481.257 us; speedup vs baseline: 1.4934x; 1.0648x over previous
//
#include <hip/hip_runtime.h>
#include <stdint.h>

#define DIN   64
#define HDIM  64
#define EIN   16
#define EHID  128     // edge hidden width
#define HH    4096    // HDIM*HDIM
#define TC    8256    // T cols: 8192 (layout s*2048 + o*32 + (k&31)) + 64 bias
#define STEPS 3

typedef short bf16x8 __attribute__((ext_vector_type(8)));
typedef float f32x4  __attribute__((ext_vector_type(4)));

__device__ __forceinline__ unsigned short f32_to_bf16(float f) {
    union { float f; uint32_t u; } v; v.f = f;
    uint32_t r = v.u + 0x7fffu + ((v.u >> 16) & 1u);   // RNE
    return (unsigned short)(r >> 16);
}
__device__ __forceinline__ float bfu_to_f(unsigned short u) {
    union { uint32_t u; float f; } v; v.u = (uint32_t)u << 16; return v.f;
}

// ---- merged prologue: [0,nbN) node_mlp | [nbN,+nbE) edge_mlp | [+nbB) bmat | rest hist ----
__global__ void k_pro(const float* __restrict__ nf, const float* __restrict__ W0,
                      const float* __restrict__ b0, float* __restrict__ outb,
                      unsigned short* __restrict__ outbf,
                      const float* __restrict__ ef, const float* __restrict__ We1,
                      const float* __restrict__ be1, unsigned short* __restrict__ h,
                      const float* __restrict__ We2, const float* __restrict__ be2,
                      unsigned short* __restrict__ BmatT,
                      const int* __restrict__ src, const int* __restrict__ dst,
                      int* __restrict__ cntS, int* __restrict__ cntD,
                      int n_nodes, int n_edges, int nbN, int nbE, int nbB) {
    __shared__ float smem[DIN * HDIM];   // 16 KB; edge path reuses first 2304 floats
    int b = blockIdx.x, tid = threadIdx.x;
    if (b < nbN) {
        // node MLP: out[n,o] = relu(n_feat[n,:]@W0[:,o]+b0[o]); 4 nodes/block
        for (int i = tid; i < DIN * HDIM; i += 256) smem[i] = W0[i];
        __syncthreads();
        int node = b * 4 + (tid >> 6);
        int o = tid & 63;
        if (node >= n_nodes) return;
        float xr = nf[node * DIN + o];
        float acc = b0[o];
#pragma unroll 8
        for (int i = 0; i < DIN; ++i)
            acc += __shfl(xr, i, 64) * smem[i * HDIM + o];
        float v = fmaxf(acc, 0.f);
        outb[node * HDIM + o] = v;
        outbf[node * HDIM + o] = f32_to_bf16(v);
    } else if (b < nbN + nbE) {
        // edge MLP: h[e,c] = relu(ef[e,:]@We1[:,c]+be1[c]) -> bf16; 16 edges/block
        float* w1s = smem;               // 2048 floats
        float* xs  = smem + EIN * EHID;  // 256 floats
        int e0 = (b - nbN) * 16;
#pragma unroll
        for (int i = tid; i < EIN * EHID; i += 256) w1s[i] = We1[i];
        xs[tid] = ef[(size_t)e0 * EIN + tid];
        __syncthreads();
        int g = tid >> 4, c0 = (tid & 15) * 8;
        int edge = e0 + g;
        if (edge >= n_edges) return;
        float acc[8];
#pragma unroll
        for (int j = 0; j < 8; ++j) acc[j] = be1[c0 + j];
#pragma unroll
        for (int i = 0; i < EIN; ++i) {
            float xi = xs[g * EIN + i];
#pragma unroll
            for (int j = 0; j < 8; ++j) acc[j] += xi * w1s[i * EHID + c0 + j];
        }
        uint32_t p0 = f32_to_bf16(fmaxf(acc[0], 0.f)) | ((uint32_t)f32_to_bf16(fmaxf(acc[1], 0.f)) << 16);
        uint32_t p1 = f32_to_bf16(fmaxf(acc[2], 0.f)) | ((uint32_t)f32_to_bf16(fmaxf(acc[3], 0.f)) << 16);
        uint32_t p2 = f32_to_bf16(fmaxf(acc[4], 0.f)) | ((uint32_t)f32_to_bf16(fmaxf(acc[5], 0.f)) << 16);
        uint32_t p3 = f32_to_bf16(fmaxf(acc[6], 0.f)) | ((uint32_t)f32_to_bf16(fmaxf(acc[7], 0.f)) << 16);
        uint4 pk = {p0, p1, p2, p3};
        *(uint4*)(h + (size_t)edge * EHID + c0) = pk;
    } else if (b < nbN + nbE + nbB) {
        // BmatT with epilogue-pack + T'' B-fragment permutations baked in
        int t = (b - nbN - nbE) * 256 + tid;
        if (t >= TC * 64) return;
        int c = t >> 6, i = t & 63;
        int g = c & 63;
        int m = (c & ~63) + 4 * (g & 15) + (g >> 4);
        float v;
        if (m < 8192) {
            int k = ((m >> 11) << 5) | (m & 31);
            int o = (m >> 5) & 63;
            v = We2[k * HH + i * 64 + o];
        } else {
            v = be2[i * 64 + (m - 8192)];
        }
        BmatT[t] = f32_to_bf16(v);
    } else {
        // histogram src and dst
        int e = (b - nbN - nbE - nbB) * 256 + tid;
        if (e >= n_edges) return;
        atomicAdd(&cntS[src[e]], 1);
        atomicAdd(&cntD[dst[e]], 1);
    }
}

// T[n, m] = sum_i x[n,i]*B[i,m], bf16 out in T'' layout.
// M=128 node tile: wave holds its 64-col B-frags in regs, loops 8 node sub-tiles
// -> BmatT traffic halved vs M=64. grid: x = col-tile(256), y = node-tile(128).
__global__ void k_T(const unsigned short* __restrict__ outbf, const unsigned short* __restrict__ BmatT,
                    unsigned short* __restrict__ T, int n0, int n1) {
    int wave = threadIdx.x >> 6, lane = threadIdx.x & 63;
    int r = lane & 15, q = lane >> 4;
    int eb = n0 + blockIdx.y * 128;
    int cb = blockIdx.x * 256 + wave * 64;
    bf16x8 bfr[4][2];
#pragma unroll
    for (int nt = 0; nt < 4; ++nt) {
        int c = cb + nt * 16 + r;
        if (c >= TC) c = 0;                  // clamped load; store guarded
        size_t cofs = (size_t)c * 64;
        bfr[nt][0] = *(const bf16x8*)(BmatT + cofs + q * 8);
        bfr[nt][1] = *(const bf16x8*)(BmatT + cofs + 32 + q * 8);
    }
    bool cok = (cb < TC);
#pragma unroll
    for (int mt = 0; mt < 8; ++mt) {
        int e = eb + mt * 16 + r;
        if (e >= n1) e = n1 - 1;
        bf16x8 afr0 = *(const bf16x8*)(outbf + (size_t)e * 64 + q * 8);
        bf16x8 afr1 = *(const bf16x8*)(outbf + (size_t)e * 64 + 32 + q * 8);
        f32x4 acc[4] = {};
#pragma unroll
        for (int nt = 0; nt < 4; ++nt) {
            acc[nt] = __builtin_amdgcn_mfma_f32_16x16x32_bf16(afr0, bfr[nt][0], acc[nt], 0, 0, 0);
            acc[nt] = __builtin_amdgcn_mfma_f32_16x16x32_bf16(afr1, bfr[nt][1], acc[nt], 0, 0, 0);
        }
        if (!cok) continue;
#pragma unroll
        for (int rg = 0; rg < 4; ++rg) {
            int n = eb + mt * 16 + q * 4 + rg;     // C/D: col=lane&15, row=quad*4+reg
            if (n >= n1) continue;
            ushort4 pk;
            pk.x = f32_to_bf16(acc[0][rg]);
            pk.y = f32_to_bf16(acc[1][rg]);
            pk.z = f32_to_bf16(acc[2][rg]);
            pk.w = f32_to_bf16(acc[3][rg]);
            *(ushort4*)(T + (size_t)(n - n0) * TC + cb + 4 * r) = pk;
        }
    }
}

// per src-node wave, MFMA: msg[tile of 16 edges][64 o] = h[edges, 0:128] @ T''[n]
__global__ void k_msg(const unsigned short* __restrict__ h, const unsigned short* __restrict__ T,
                      const int* __restrict__ offS, const int* __restrict__ permS,
                      float* __restrict__ msg, int n0, int n1) {
    int wave = threadIdx.x >> 6, lane = threadIdx.x & 63;
    int n = n0 + blockIdx.x * 4 + wave;
    if (n >= n1) return;
    int beg = offS[n], end = offS[n + 1];
    if (beg == end) return;
    int r = lane & 15, q = lane >> 4;
    const unsigned short* Tb = T + (size_t)(n - n0) * TC;
    float bias[4];
#pragma unroll
    for (int nt = 0; nt < 4; ++nt)
        bias[nt] = bfu_to_f(Tb[8192 + nt * 16 + r]);
    for (int j0 = beg; j0 < end; j0 += 16) {
        int jc = j0 + r; if (jc >= end) jc = end - 1;
        int e = permS[jc];
        const unsigned short* he = h + (size_t)e * EHID;
        f32x4 acc[4] = {};
#pragma unroll
        for (int s = 0; s < 4; ++s) {        // K = 128 = 4*32
            bf16x8 afr = *(const bf16x8*)(he + s * 32 + q * 8);
#pragma unroll
            for (int nt = 0; nt < 4; ++nt) {
                bf16x8 bfr = *(const bf16x8*)(Tb + s * 2048 + (nt * 16 + r) * 32 + q * 8);
                acc[nt] = __builtin_amdgcn_mfma_f32_16x16x32_bf16(afr, bfr, acc[nt], 0, 0, 0);
            }
        }
#pragma unroll
        for (int rg = 0; rg < 4; ++rg) {
            int jr = j0 + q * 4 + rg;
            if (jr >= end) continue;
            int er = permS[jr];
#pragma unroll
            for (int nt = 0; nt < 4; ++nt)
                msg[(size_t)er * 64 + nt * 16 + r] = acc[nt][rg] + bias[nt];
        }
    }
}

// exclusive prefix sum (one block per array; blockIdx.x: 0=S, 1=D)
__global__ void k_scan(const int* __restrict__ cntS, const int* __restrict__ cntD,
                       int* __restrict__ offS, int* __restrict__ offD,
                       int* __restrict__ curS, int* __restrict__ curD, int n, int total) {
    const int* cnt = blockIdx.x ? cntD : cntS;
    int* off = blockIdx.x ? offD : offS;
    int* cur = blockIdx.x ? curD : curS;
    __shared__ int part[256];
    int tid = threadIdx.x;
    int chunk = (n + 255) / 256;
    int c0 = tid * chunk, c1 = c0 + chunk; if (c1 > n) c1 = n; if (c0 > n) c0 = n;
    int s = 0;
    for (int i = c0; i < c1; ++i) s += cnt[i];
    part[tid] = s;
    __syncthreads();
    for (int st = 1; st < 256; st <<= 1) {
        int v = (tid >= st) ? part[tid - st] : 0;
        __syncthreads();
        part[tid] += v;
        __syncthreads();
    }
    int run = tid ? part[tid - 1] : 0;
    for (int i = c0; i < c1; ++i) { off[i] = run; cur[i] = run; run += cnt[i]; }
    if (tid == 0) off[n] = total;
}

__global__ void k_perm(const int* __restrict__ src, const int* __restrict__ dst,
                       int* __restrict__ curS, int* __restrict__ curD,
                       int* __restrict__ permS, int* __restrict__ permD, int n_edges) {
    int e = blockIdx.x * 256 + threadIdx.x;
    if (e >= n_edges) return;
    permS[atomicAdd(&curS[src[e]], 1)] = e;
    permD[atomicAdd(&curD[dst[e]], 1)] = e;
}

// per dst-node wave: out[d] = relu(sum msg + cbias); atomic-free
__global__ void k_agg(const float* __restrict__ msg, const int* __restrict__ offD,
                      const int* __restrict__ permD, const float* __restrict__ cbias,
                      float* __restrict__ outb, unsigned short* __restrict__ outbf, int n_nodes) {
    int wave = threadIdx.x >> 6, lane = threadIdx.x & 63;
    int d = blockIdx.x * 4 + wave;
    if (d >= n_nodes) return;
    float acc = 0.f;
    int end = offD[d + 1];
    for (int j = offD[d]; j < end; ++j)
        acc += msg[(size_t)permD[j] * 64 + lane];
    float v = fmaxf(acc + cbias[lane], 0.f);
    outb[(size_t)d * 64 + lane] = v;
    outbf[(size_t)d * 64 + lane] = f32_to_bf16(v);
}

// grid MUST be 64 blocks (row stride 256 hardcoded)
__global__ void k_bn_stats(const float* __restrict__ out, float* __restrict__ stat, int n_nodes) {
    __shared__ float s1[256], s2[256];
    int tid = threadIdx.x;
    int f = tid & 63, g = tid >> 6;
    float sum = 0.f, ss = 0.f;
    for (int r = blockIdx.x * 4 + g; r < n_nodes; r += 256) {
        float v = out[r * HDIM + f];
        sum += v; ss += v * v;
    }
    s1[tid] = sum; s2[tid] = ss;
    __syncthreads();
    if (tid < 64) {
        float A = s1[tid] + s1[64 + tid] + s1[128 + tid] + s1[192 + tid];
        float B = s2[tid] + s2[64 + tid] + s2[128 + tid] + s2[192 + tid];
        atomicAdd(&stat[tid], A);
        atomicAdd(&stat[64 + tid], B);
    }
}

// bn_final fused in: every thread derives scale/shift from stat (identical arith)
__global__ void k_bn_apply(const float* __restrict__ out, const float* __restrict__ stat,
                           const float* __restrict__ gamma, const float* __restrict__ beta,
                           float* __restrict__ y, int n, int n_nodes) {
    int t = blockIdx.x * 256 + threadIdx.x;
    if (t >= n) return;
    int f = t & 63;
    float mean = stat[f] / n_nodes;
    float var  = stat[64 + f] / n_nodes - mean * mean;   // population var
    float inv  = rsqrtf(var + 1e-5f);
    float scale = gamma[f] * inv;
    float shift = beta[f] - mean * scale;
    y[t] = out[t] * scale + shift;
}

extern "C" void kernel_launch(void* const* d_in, const int* in_sizes, int n_in,
                              void* d_out, int out_size, void* d_ws, size_t ws_size,
                              hipStream_t stream) {
    const float* nf    = (const float*)d_in[0];
    const float* ef    = (const float*)d_in[1];
    const int*   src   = (const int*)d_in[2];
    const int*   dst   = (const int*)d_in[3];
    const float* W0    = (const float*)d_in[4];
    const float* b0    = (const float*)d_in[5];
    const float* We1   = (const float*)d_in[6];
    const float* be1   = (const float*)d_in[7];
    const float* We2   = (const float*)d_in[8];
    const float* be2   = (const float*)d_in[9];
    const float* cbias = (const float*)d_in[10];
    const float* gamma = (const float*)d_in[11];
    const float* beta  = (const float*)d_in[12];
    (void)n_in; (void)out_size;

    int n_nodes = in_sizes[0] / DIN;   // 10000
    int n_edges = in_sizes[2];         // 100000

    char* ws = (char*)d_ws;
    size_t off = 0;
    auto carve = [&](size_t bytes) -> void* {
        void* p = ws + off;
        off = (off + bytes + 255) & ~(size_t)255;
        return p;
    };
    unsigned short* h     = (unsigned short*)carve((size_t)n_edges * EHID * 2);  // 25.6 MB
    float*          msg   = (float*)carve((size_t)n_edges * 64 * 4);             // 25.6 MB
    float*          outb  = (float*)carve((size_t)n_nodes * HDIM * 4);
    unsigned short* outbf = (unsigned short*)carve((size_t)n_nodes * HDIM * 2);
    unsigned short* BmatT = (unsigned short*)carve((size_t)TC * 64 * 2);
    int*            offS  = (int*)carve((size_t)(n_nodes + 1) * 4);
    int*            offD  = (int*)carve((size_t)(n_nodes + 1) * 4);
    int*            curS  = (int*)carve((size_t)n_nodes * 4);
    int*            curD  = (int*)carve((size_t)n_nodes * 4);
    int*            permS = (int*)carve((size_t)n_edges * 4);
    int*            permD = (int*)carve((size_t)n_edges * 4);
    float*          stat  = (float*)carve(128 * 4 + (size_t)2 * n_nodes * 4); // stat + cntS + cntD
    int*            cntS  = (int*)(stat + 128);
    int*            cntD  = cntS + n_nodes;
    unsigned short* T     = (unsigned short*)(ws + off);
    size_t avail = ws_size > off ? ws_size - off : 0;
    long tcap = (long)(avail / ((size_t)TC * 2));   // ws-capacity bound (node rows)
    if (tcap > n_nodes) tcap = n_nodes;
    if (tcap < 64) tcap = 64;
    // L3-residency: ~83 MB T chunk stays in the 256 MB Infinity Cache
    long half = (((long)n_nodes + 1) / 2 + 63) & ~63L;   // 5056 for n=10000
    long tchunk = tcap < half ? tcap : half;

    hipMemsetAsync(stat, 0, 128 * 4 + (size_t)2 * n_nodes * 4, stream);

    int nbN = (n_nodes + 3) / 4;            // 2500
    int nbE = (n_edges + 15) / 16;          // 6250
    int nbB = (TC * 64 + 255) / 256;        // 2064
    int nbH = (n_edges + 255) / 256;        // 391
    k_pro<<<dim3(nbN + nbE + nbB + nbH), 256, 0, stream>>>(
        nf, W0, b0, outb, outbf, ef, We1, be1, h, We2, be2, BmatT,
        src, dst, cntS, cntD, n_nodes, n_edges, nbN, nbE, nbB);
    k_scan<<<dim3(2), 256, 0, stream>>>(cntS, cntD, offS, offD, curS, curD, n_nodes, n_edges);
    k_perm<<<dim3((n_edges + 255) / 256), 256, 0, stream>>>(src, dst, curS, curD, permS, permD, n_edges);

    for (int step = 0; step < STEPS; ++step) {
        for (long n0 = 0; n0 < n_nodes; n0 += tchunk) {
            long n1 = n0 + tchunk; if (n1 > n_nodes) n1 = n_nodes;
            long cnt = n1 - n0;
            k_T<<<dim3((TC + 255) / 256, (cnt + 127) / 128), 256, 0, stream>>>(
                outbf, BmatT, T, (int)n0, (int)n1);
            k_msg<<<dim3((cnt + 3) / 4), 256, 0, stream>>>(
                h, T, offS, permS, msg, (int)n0, (int)n1);
        }
        k_agg<<<dim3((n_nodes + 3) / 4), 256, 0, stream>>>(msg, offD, permD, cbias, outb, outbf, n_nodes);
    }

    k_bn_stats<<<dim3(64), 256, 0, stream>>>(outb, stat, n_nodes);
    k_bn_apply<<<dim3((n_nodes * HDIM + 255) / 256), 256, 0, stream>>>(
        outb, stat, gamma, beta, (float*)d_out, n_nodes * HDIM, n_nodes);
}

// Round 9
// 436.671 us; speedup vs baseline: 1.6459x; 1.1021x over previous
//
#include <hip/hip_runtime.h>
#include <stdint.h>

#define DIN   64
#define HDIM  64
#define EIN   16
#define EHID  128     // edge hidden width
#define HH    4096    // HDIM*HDIM
#define TC    8256    // T cols: 8192 (layout s*2048 + o*32 + (k&31)) + 64 bias
#define STEPS 3

typedef short bf16x8 __attribute__((ext_vector_type(8)));
typedef float f32x4  __attribute__((ext_vector_type(4)));

__device__ __forceinline__ unsigned short f32_to_bf16(float f) {
    union { float f; uint32_t u; } v; v.f = f;
    uint32_t r = v.u + 0x7fffu + ((v.u >> 16) & 1u);   // RNE
    return (unsigned short)(r >> 16);
}
__device__ __forceinline__ float bfu_to_f(unsigned short u) {
    union { uint32_t u; float f; } v; v.u = (uint32_t)u << 16; return v.f;
}

// ---- merged prologue: [0,nbN) node_mlp | [nbN,+nbE) edge_mlp(MFMA) | [+nbB) bmat | rest hist ----
__global__ void k_pro(const float* __restrict__ nf, const float* __restrict__ W0,
                      const float* __restrict__ b0, float* __restrict__ outb,
                      unsigned short* __restrict__ outbf,
                      const float* __restrict__ ef, const float* __restrict__ We1,
                      const float* __restrict__ be1, unsigned short* __restrict__ h,
                      const float* __restrict__ We2, const float* __restrict__ be2,
                      unsigned short* __restrict__ BmatT,
                      const int* __restrict__ src, const int* __restrict__ dst,
                      int* __restrict__ cntS, int* __restrict__ cntD,
                      int n_nodes, int n_edges, int nbN, int nbE, int nbB) {
    __shared__ float smem[DIN * HDIM];   // 16 KB (node path only)
    int b = blockIdx.x, tid = threadIdx.x;
    if (b < nbN) {
        // node MLP: out[n,o] = relu(n_feat[n,:]@W0[:,o]+b0[o]); 4 nodes/block
        for (int i = tid; i < DIN * HDIM; i += 256) smem[i] = W0[i];
        __syncthreads();
        int node = b * 4 + (tid >> 6);
        int o = tid & 63;
        if (node >= n_nodes) return;
        float xr = nf[node * DIN + o];
        float acc = b0[o];
#pragma unroll 8
        for (int i = 0; i < DIN; ++i)
            acc += __shfl(xr, i, 64) * smem[i * HDIM + o];
        float v = fmaxf(acc, 0.f);
        outb[node * HDIM + o] = v;
        outbf[node * HDIM + o] = f32_to_bf16(v);
    } else if (b < nbN + nbE) {
        // edge MLP via MFMA: 64 edges/block (16/wave), K=16 zero-padded to 32.
        // h stored with per-64-group col perm: h_mem[64a+4r+t] = h_true[64a+t*16+r]
        // (k_bmat applies the inverse perm on its k index).
        int wave = tid >> 6, lane = tid & 63;
        int r = lane & 15, q = lane >> 4;
        int e0 = (b - nbN) * 64 + wave * 16;
        if (e0 >= n_edges) return;           // wave-uniform
        bf16x8 afr = (bf16x8){};
        bf16x8 bfr[8];
#pragma unroll
        for (int nt = 0; nt < 8; ++nt) bfr[nt] = (bf16x8){};
        if (q < 2) {
            int ea = e0 + r; if (ea >= n_edges) ea = n_edges - 1;
            const float* xa = ef + (size_t)ea * EIN + q * 8;
#pragma unroll
            for (int j = 0; j < 8; ++j) afr[j] = (short)f32_to_bf16(xa[j]);
#pragma unroll
            for (int nt = 0; nt < 8; ++nt)
#pragma unroll
                for (int j = 0; j < 8; ++j)
                    bfr[nt][j] = (short)f32_to_bf16(We1[(q * 8 + j) * EHID + nt * 16 + r]);
        }
        f32x4 acc[8];
#pragma unroll
        for (int nt = 0; nt < 8; ++nt)
            acc[nt] = __builtin_amdgcn_mfma_f32_16x16x32_bf16(afr, bfr[nt], (f32x4){}, 0, 0, 0);
        float bias[8];
#pragma unroll
        for (int nt = 0; nt < 8; ++nt) bias[nt] = be1[nt * 16 + r];
#pragma unroll
        for (int rg = 0; rg < 4; ++rg) {
            int e = e0 + q * 4 + rg;         // C/D: col=lane&15, row=quad*4+reg
            if (e >= n_edges) continue;
            ushort4 pk0, pk1;
            pk0.x = f32_to_bf16(fmaxf(acc[0][rg] + bias[0], 0.f));
            pk0.y = f32_to_bf16(fmaxf(acc[1][rg] + bias[1], 0.f));
            pk0.z = f32_to_bf16(fmaxf(acc[2][rg] + bias[2], 0.f));
            pk0.w = f32_to_bf16(fmaxf(acc[3][rg] + bias[3], 0.f));
            pk1.x = f32_to_bf16(fmaxf(acc[4][rg] + bias[4], 0.f));
            pk1.y = f32_to_bf16(fmaxf(acc[5][rg] + bias[5], 0.f));
            pk1.z = f32_to_bf16(fmaxf(acc[6][rg] + bias[6], 0.f));
            pk1.w = f32_to_bf16(fmaxf(acc[7][rg] + bias[7], 0.f));
            *(ushort4*)(h + (size_t)e * EHID + 4 * r) = pk0;
            *(ushort4*)(h + (size_t)e * EHID + 64 + 4 * r) = pk1;
        }
    } else if (b < nbN + nbE + nbB) {
        // BmatT: epilogue-pack perm + T'' layout + h-storage perm (sigma) baked in
        int t = (b - nbN - nbE) * 256 + tid;
        if (t >= TC * 64) return;
        int c = t >> 6, i = t & 63;
        int g = c & 63;
        int m = (c & ~63) + 4 * (g & 15) + (g >> 4);
        float v;
        if (m < 8192) {
            int p = ((m >> 11) << 5) | (m & 31);                     // stored h position
            int k = (p & 64) + ((p & 3) << 4) + ((p >> 2) & 15);     // true h channel
            int o = (m >> 5) & 63;
            v = We2[k * HH + i * 64 + o];
        } else {
            v = be2[i * 64 + (m - 8192)];
        }
        BmatT[t] = f32_to_bf16(v);
    } else {
        // histogram src and dst
        int e = (b - nbN - nbE - nbB) * 256 + tid;
        if (e >= n_edges) return;
        atomicAdd(&cntS[src[e]], 1);
        atomicAdd(&cntD[dst[e]], 1);
    }
}

// T[n, m] = sum_i x[n,i]*B[i,m], bf16 out in T'' layout.
// M=128 node tile: wave holds 64-col B-frags in regs, loops 8 node sub-tiles.
__global__ void k_T(const unsigned short* __restrict__ outbf, const unsigned short* __restrict__ BmatT,
                    unsigned short* __restrict__ T, int n0, int n1) {
    int wave = threadIdx.x >> 6, lane = threadIdx.x & 63;
    int r = lane & 15, q = lane >> 4;
    int eb = n0 + blockIdx.y * 128;
    int cb = blockIdx.x * 256 + wave * 64;
    bf16x8 bfr[4][2];
#pragma unroll
    for (int nt = 0; nt < 4; ++nt) {
        int c = cb + nt * 16 + r;
        if (c >= TC) c = 0;                  // clamped load; store guarded
        size_t cofs = (size_t)c * 64;
        bfr[nt][0] = *(const bf16x8*)(BmatT + cofs + q * 8);
        bfr[nt][1] = *(const bf16x8*)(BmatT + cofs + 32 + q * 8);
    }
    bool cok = (cb < TC);
#pragma unroll
    for (int mt = 0; mt < 8; ++mt) {
        int e = eb + mt * 16 + r;
        if (e >= n1) e = n1 - 1;
        bf16x8 afr0 = *(const bf16x8*)(outbf + (size_t)e * 64 + q * 8);
        bf16x8 afr1 = *(const bf16x8*)(outbf + (size_t)e * 64 + 32 + q * 8);
        f32x4 acc[4] = {};
#pragma unroll
        for (int nt = 0; nt < 4; ++nt) {
            acc[nt] = __builtin_amdgcn_mfma_f32_16x16x32_bf16(afr0, bfr[nt][0], acc[nt], 0, 0, 0);
            acc[nt] = __builtin_amdgcn_mfma_f32_16x16x32_bf16(afr1, bfr[nt][1], acc[nt], 0, 0, 0);
        }
        if (!cok) continue;
#pragma unroll
        for (int rg = 0; rg < 4; ++rg) {
            int n = eb + mt * 16 + q * 4 + rg;     // C/D: col=lane&15, row=quad*4+reg
            if (n >= n1) continue;
            ushort4 pk;
            pk.x = f32_to_bf16(acc[0][rg]);
            pk.y = f32_to_bf16(acc[1][rg]);
            pk.z = f32_to_bf16(acc[2][rg]);
            pk.w = f32_to_bf16(acc[3][rg]);
            *(ushort4*)(T + (size_t)(n - n0) * TC + cb + 4 * r) = pk;
        }
    }
}

// per src-node wave, MFMA: msg[tile of 16 edges][64 o] = h[edges, 0:128] @ T''[n]
__global__ void k_msg(const unsigned short* __restrict__ h, const unsigned short* __restrict__ T,
                      const int* __restrict__ offS, const int* __restrict__ permS,
                      float* __restrict__ msg, int n0, int n1) {
    int wave = threadIdx.x >> 6, lane = threadIdx.x & 63;
    int n = n0 + blockIdx.x * 4 + wave;
    if (n >= n1) return;
    int beg = offS[n], end = offS[n + 1];
    if (beg == end) return;
    int r = lane & 15, q = lane >> 4;
    const unsigned short* Tb = T + (size_t)(n - n0) * TC;
    float bias[4];
#pragma unroll
    for (int nt = 0; nt < 4; ++nt)
        bias[nt] = bfu_to_f(Tb[8192 + nt * 16 + r]);
    for (int j0 = beg; j0 < end; j0 += 16) {
        int jc = j0 + r; if (jc >= end) jc = end - 1;
        int e = permS[jc];
        const unsigned short* he = h + (size_t)e * EHID;
        f32x4 acc[4] = {};
#pragma unroll
        for (int s = 0; s < 4; ++s) {        // K = 128 = 4*32
            bf16x8 afr = *(const bf16x8*)(he + s * 32 + q * 8);
#pragma unroll
            for (int nt = 0; nt < 4; ++nt) {
                bf16x8 bfr = *(const bf16x8*)(Tb + s * 2048 + (nt * 16 + r) * 32 + q * 8);
                acc[nt] = __builtin_amdgcn_mfma_f32_16x16x32_bf16(afr, bfr, acc[nt], 0, 0, 0);
            }
        }
#pragma unroll
        for (int rg = 0; rg < 4; ++rg) {
            int jr = j0 + q * 4 + rg;
            if (jr >= end) continue;
            int er = permS[jr];
#pragma unroll
            for (int nt = 0; nt < 4; ++nt)
                msg[(size_t)er * 64 + nt * 16 + r] = acc[nt][rg] + bias[nt];
        }
    }
}

// exclusive prefix sum (one block per array; blockIdx.x: 0=S, 1=D)
__global__ void k_scan(const int* __restrict__ cntS, const int* __restrict__ cntD,
                       int* __restrict__ offS, int* __restrict__ offD,
                       int* __restrict__ curS, int* __restrict__ curD, int n, int total) {
    const int* cnt = blockIdx.x ? cntD : cntS;
    int* off = blockIdx.x ? offD : offS;
    int* cur = blockIdx.x ? curD : curS;
    __shared__ int part[256];
    int tid = threadIdx.x;
    int chunk = (n + 255) / 256;
    int c0 = tid * chunk, c1 = c0 + chunk; if (c1 > n) c1 = n; if (c0 > n) c0 = n;
    int s = 0;
    for (int i = c0; i < c1; ++i) s += cnt[i];
    part[tid] = s;
    __syncthreads();
    for (int st = 1; st < 256; st <<= 1) {
        int v = (tid >= st) ? part[tid - st] : 0;
        __syncthreads();
        part[tid] += v;
        __syncthreads();
    }
    int run = tid ? part[tid - 1] : 0;
    for (int i = c0; i < c1; ++i) { off[i] = run; cur[i] = run; run += cnt[i]; }
    if (tid == 0) off[n] = total;
}

__global__ void k_perm(const int* __restrict__ src, const int* __restrict__ dst,
                       int* __restrict__ curS, int* __restrict__ curD,
                       int* __restrict__ permS, int* __restrict__ permD, int n_edges) {
    int e = blockIdx.x * 256 + threadIdx.x;
    if (e >= n_edges) return;
    permS[atomicAdd(&curS[src[e]], 1)] = e;
    permD[atomicAdd(&curD[dst[e]], 1)] = e;
}

// per dst-node wave: out[d] = relu(sum msg + cbias); atomic-free
__global__ void k_agg(const float* __restrict__ msg, const int* __restrict__ offD,
                      const int* __restrict__ permD, const float* __restrict__ cbias,
                      float* __restrict__ outb, unsigned short* __restrict__ outbf, int n_nodes) {
    int wave = threadIdx.x >> 6, lane = threadIdx.x & 63;
    int d = blockIdx.x * 4 + wave;
    if (d >= n_nodes) return;
    float acc = 0.f;
    int end = offD[d + 1];
    for (int j = offD[d]; j < end; ++j)
        acc += msg[(size_t)permD[j] * 64 + lane];
    float v = fmaxf(acc + cbias[lane], 0.f);
    outb[(size_t)d * 64 + lane] = v;
    outbf[(size_t)d * 64 + lane] = f32_to_bf16(v);
}

// grid MUST be 64 blocks (row stride 256 hardcoded)
__global__ void k_bn_stats(const float* __restrict__ out, float* __restrict__ stat, int n_nodes) {
    __shared__ float s1[256], s2[256];
    int tid = threadIdx.x;
    int f = tid & 63, g = tid >> 6;
    float sum = 0.f, ss = 0.f;
    for (int r = blockIdx.x * 4 + g; r < n_nodes; r += 256) {
        float v = out[r * HDIM + f];
        sum += v; ss += v * v;
    }
    s1[tid] = sum; s2[tid] = ss;
    __syncthreads();
    if (tid < 64) {
        float A = s1[tid] + s1[64 + tid] + s1[128 + tid] + s1[192 + tid];
        float B = s2[tid] + s2[64 + tid] + s2[128 + tid] + s2[192 + tid];
        atomicAdd(&stat[tid], A);
        atomicAdd(&stat[64 + tid], B);
    }
}

// bn_final fused in: every thread derives scale/shift from stat (identical arith)
__global__ void k_bn_apply(const float* __restrict__ out, const float* __restrict__ stat,
                           const float* __restrict__ gamma, const float* __restrict__ beta,
                           float* __restrict__ y, int n, int n_nodes) {
    int t = blockIdx.x * 256 + threadIdx.x;
    if (t >= n) return;
    int f = t & 63;
    float mean = stat[f] / n_nodes;
    float var  = stat[64 + f] / n_nodes - mean * mean;   // population var
    float inv  = rsqrtf(var + 1e-5f);
    float scale = gamma[f] * inv;
    float shift = beta[f] - mean * scale;
    y[t] = out[t] * scale + shift;
}

extern "C" void kernel_launch(void* const* d_in, const int* in_sizes, int n_in,
                              void* d_out, int out_size, void* d_ws, size_t ws_size,
                              hipStream_t stream) {
    const float* nf    = (const float*)d_in[0];
    const float* ef    = (const float*)d_in[1];
    const int*   src   = (const int*)d_in[2];
    const int*   dst   = (const int*)d_in[3];
    const float* W0    = (const float*)d_in[4];
    const float* b0    = (const float*)d_in[5];
    const float* We1   = (const float*)d_in[6];
    const float* be1   = (const float*)d_in[7];
    const float* We2   = (const float*)d_in[8];
    const float* be2   = (const float*)d_in[9];
    const float* cbias = (const float*)d_in[10];
    const float* gamma = (const float*)d_in[11];
    const float* beta  = (const float*)d_in[12];
    (void)n_in; (void)out_size;

    int n_nodes = in_sizes[0] / DIN;   // 10000
    int n_edges = in_sizes[2];         // 100000

    char* ws = (char*)d_ws;
    size_t off = 0;
    auto carve = [&](size_t bytes) -> void* {
        void* p = ws + off;
        off = (off + bytes + 255) & ~(size_t)255;
        return p;
    };
    unsigned short* h     = (unsigned short*)carve((size_t)n_edges * EHID * 2);  // 25.6 MB
    float*          msg   = (float*)carve((size_t)n_edges * 64 * 4);             // 25.6 MB
    float*          outb  = (float*)carve((size_t)n_nodes * HDIM * 4);
    unsigned short* outbf = (unsigned short*)carve((size_t)n_nodes * HDIM * 2);
    unsigned short* BmatT = (unsigned short*)carve((size_t)TC * 64 * 2);
    int*            offS  = (int*)carve((size_t)(n_nodes + 1) * 4);
    int*            offD  = (int*)carve((size_t)(n_nodes + 1) * 4);
    int*            curS  = (int*)carve((size_t)n_nodes * 4);
    int*            curD  = (int*)carve((size_t)n_nodes * 4);
    int*            permS = (int*)carve((size_t)n_edges * 4);
    int*            permD = (int*)carve((size_t)n_edges * 4);
    float*          stat  = (float*)carve(128 * 4 + (size_t)2 * n_nodes * 4); // stat + cntS + cntD
    int*            cntS  = (int*)(stat + 128);
    int*            cntD  = cntS + n_nodes;
    unsigned short* T     = (unsigned short*)(ws + off);
    size_t avail = ws_size > off ? ws_size - off : 0;
    long tcap = (long)(avail / ((size_t)TC * 2));   // ws-capacity bound (node rows)
    if (tcap > n_nodes) tcap = n_nodes;
    if (tcap < 64) tcap = 64;
    long tchunk = tcap;   // R7: chunking measured neutral -> single chunk, fewer launches

    hipMemsetAsync(stat, 0, 128 * 4 + (size_t)2 * n_nodes * 4, stream);

    int nbN = (n_nodes + 3) / 4;            // 2500
    int nbE = (n_edges + 63) / 64;          // 1563 (MFMA edge path: 64 edges/block)
    int nbB = (TC * 64 + 255) / 256;        // 2064
    int nbH = (n_edges + 255) / 256;        // 391
    k_pro<<<dim3(nbN + nbE + nbB + nbH), 256, 0, stream>>>(
        nf, W0, b0, outb, outbf, ef, We1, be1, h, We2, be2, BmatT,
        src, dst, cntS, cntD, n_nodes, n_edges, nbN, nbE, nbB);
    k_scan<<<dim3(2), 256, 0, stream>>>(cntS, cntD, offS, offD, curS, curD, n_nodes, n_edges);
    k_perm<<<dim3((n_edges + 255) / 256), 256, 0, stream>>>(src, dst, curS, curD, permS, permD, n_edges);

    for (int step = 0; step < STEPS; ++step) {
        for (long n0 = 0; n0 < n_nodes; n0 += tchunk) {
            long n1 = n0 + tchunk; if (n1 > n_nodes) n1 = n_nodes;
            long cnt = n1 - n0;
            k_T<<<dim3((TC + 255) / 256, (cnt + 127) / 128), 256, 0, stream>>>(
                outbf, BmatT, T, (int)n0, (int)n1);
            k_msg<<<dim3((cnt + 3) / 4), 256, 0, stream>>>(
                h, T, offS, permS, msg, (int)n0, (int)n1);
        }
        k_agg<<<dim3((n_nodes + 3) / 4), 256, 0, stream>>>(msg, offD, permD, cbias, outb, outbf, n_nodes);
    }

    k_bn_stats<<<dim3(64), 256, 0, stream>>>(outb, stat, n_nodes);
    k_bn_apply<<<dim3((n_nodes * HDIM + 255) / 256), 256, 0, stream>>>(
        outb, stat, gamma, beta, (float*)d_out, n_nodes * HDIM, n_nodes);
}

// Round 10
// 427.842 us; speedup vs baseline: 1.6799x; 1.0206x over previous
//
#include <hip/hip_runtime.h>
#include <stdint.h>

#define DIN   64
#define HDIM  64
#define EIN   16
#define EHID  128     // edge hidden width
#define HH    4096    // HDIM*HDIM
#define TC    8256    // T cols: 8192 main + 64 bias
#define STEPS 3

typedef short bf16x8 __attribute__((ext_vector_type(8)));
typedef float f32x4  __attribute__((ext_vector_type(4)));

__device__ __forceinline__ unsigned short f32_to_bf16(float f) {
    union { float f; uint32_t u; } v; v.f = f;
    uint32_t r = v.u + 0x7fffu + ((v.u >> 16) & 1u);   // RNE
    return (unsigned short)(r >> 16);
}
__device__ __forceinline__ float bfu_to_f(unsigned short u) {
    union { uint32_t u; float f; } v; v.u = (uint32_t)u << 16; return v.f;
}

// ---- merged prologue: [0,nbN) node_mlp | [nbN,+nbE) edge_mlp(MFMA) | [+nbB) bmat | rest hist ----
__global__ void k_pro(const float* __restrict__ nf, const float* __restrict__ W0,
                      const float* __restrict__ b0, float* __restrict__ outb,
                      unsigned short* __restrict__ outbf,
                      const float* __restrict__ ef, const float* __restrict__ We1,
                      const float* __restrict__ be1, unsigned short* __restrict__ h,
                      const float* __restrict__ We2, const float* __restrict__ be2,
                      unsigned short* __restrict__ BmatT,
                      const int* __restrict__ src, const int* __restrict__ dst,
                      int* __restrict__ cntS, int* __restrict__ cntD,
                      int n_nodes, int n_edges, int nbN, int nbE, int nbB) {
    __shared__ float smem[DIN * HDIM];   // 16 KB (node path only)
    int b = blockIdx.x, tid = threadIdx.x;
    if (b < nbN) {
        // node MLP: out[n,o] = relu(n_feat[n,:]@W0[:,o]+b0[o]); 4 nodes/block
        for (int i = tid; i < DIN * HDIM; i += 256) smem[i] = W0[i];
        __syncthreads();
        int node = b * 4 + (tid >> 6);
        int o = tid & 63;
        if (node >= n_nodes) return;
        float xr = nf[node * DIN + o];
        float acc = b0[o];
#pragma unroll 8
        for (int i = 0; i < DIN; ++i)
            acc += __shfl(xr, i, 64) * smem[i * HDIM + o];
        float v = fmaxf(acc, 0.f);
        outb[node * HDIM + o] = v;
        outbf[node * HDIM + o] = f32_to_bf16(v);
    } else if (b < nbN + nbE) {
        // edge MLP via MFMA: 64 edges/block (16/wave), K=16 zero-padded to 32.
        // h stored with per-64-group col perm sigma (inverse baked into BmatT k-index).
        int wave = tid >> 6, lane = tid & 63;
        int r = lane & 15, q = lane >> 4;
        int e0 = (b - nbN) * 64 + wave * 16;
        if (e0 >= n_edges) return;           // wave-uniform
        bf16x8 afr = (bf16x8){};
        bf16x8 bfr[8];
#pragma unroll
        for (int nt = 0; nt < 8; ++nt) bfr[nt] = (bf16x8){};
        if (q < 2) {
            int ea = e0 + r; if (ea >= n_edges) ea = n_edges - 1;
            const float* xa = ef + (size_t)ea * EIN + q * 8;
#pragma unroll
            for (int j = 0; j < 8; ++j) afr[j] = (short)f32_to_bf16(xa[j]);
#pragma unroll
            for (int nt = 0; nt < 8; ++nt)
#pragma unroll
                for (int j = 0; j < 8; ++j)
                    bfr[nt][j] = (short)f32_to_bf16(We1[(q * 8 + j) * EHID + nt * 16 + r]);
        }
        f32x4 acc[8];
#pragma unroll
        for (int nt = 0; nt < 8; ++nt)
            acc[nt] = __builtin_amdgcn_mfma_f32_16x16x32_bf16(afr, bfr[nt], (f32x4){}, 0, 0, 0);
        float bias[8];
#pragma unroll
        for (int nt = 0; nt < 8; ++nt) bias[nt] = be1[nt * 16 + r];
#pragma unroll
        for (int rg = 0; rg < 4; ++rg) {
            int e = e0 + q * 4 + rg;         // C/D: col=lane&15, row=quad*4+reg
            if (e >= n_edges) continue;
            ushort4 pk0, pk1;
            pk0.x = f32_to_bf16(fmaxf(acc[0][rg] + bias[0], 0.f));
            pk0.y = f32_to_bf16(fmaxf(acc[1][rg] + bias[1], 0.f));
            pk0.z = f32_to_bf16(fmaxf(acc[2][rg] + bias[2], 0.f));
            pk0.w = f32_to_bf16(fmaxf(acc[3][rg] + bias[3], 0.f));
            pk1.x = f32_to_bf16(fmaxf(acc[4][rg] + bias[4], 0.f));
            pk1.y = f32_to_bf16(fmaxf(acc[5][rg] + bias[5], 0.f));
            pk1.z = f32_to_bf16(fmaxf(acc[6][rg] + bias[6], 0.f));
            pk1.w = f32_to_bf16(fmaxf(acc[7][rg] + bias[7], 0.f));
            *(ushort4*)(h + (size_t)e * EHID + 4 * r) = pk0;
            *(ushort4*)(h + (size_t)e * EHID + 64 + 4 * r) = pk1;
        }
    } else if (b < nbN + nbE + nbB) {
        // BmatT: epilogue-pack perm (128-group main / 64-group bias) + T'' layout + h-perm sigma
        int t = (b - nbN - nbE) * 256 + tid;
        if (t >= TC * 64) return;
        int c = t >> 6, i = t & 63;
        int m;
        if (c < 8192) {
            int g = c & 127;                       // mfma col nt*16+r -> mem col 8r+nt
            m = (c & ~127) + 8 * (g & 15) + (g >> 4);
        } else {
            int g = c & 63;                        // bias block keeps 4r+nt
            m = (c & ~63) + 4 * (g & 15) + (g >> 4);
        }
        float v;
        if (m < 8192) {
            int p = ((m >> 11) << 5) | (m & 31);                     // stored h position
            int k = (p & 64) + ((p & 3) << 4) + ((p >> 2) & 15);     // true h channel
            int o = (m >> 5) & 63;
            v = We2[k * HH + i * 64 + o];
        } else {
            v = be2[i * 64 + (m - 8192)];
        }
        BmatT[t] = f32_to_bf16(v);
    } else {
        // histogram src and dst
        int e = (b - nbN - nbE - nbB) * 256 + tid;
        if (e >= n_edges) return;
        atomicAdd(&cntS[src[e]], 1);
        atomicAdd(&cntD[dst[e]], 1);
    }
}

// T[n, m] = sum_i x[n,i]*B[i,m], bf16 out in T'' layout.
// Main path (blockIdx.x<16): wave = 128-col group, 8 B-tiles in regs, lane packs
// 8 bf16 -> one 16-B store. Tail block 16: 64 bias cols, old 4r+nt packing.
__global__ void k_T(const unsigned short* __restrict__ outbf, const unsigned short* __restrict__ BmatT,
                    unsigned short* __restrict__ T, int n0, int n1) {
    int wave = threadIdx.x >> 6, lane = threadIdx.x & 63;
    int r = lane & 15, q = lane >> 4;
    int eb = n0 + blockIdx.y * 128;
    if (blockIdx.x < 16) {
        int cb = blockIdx.x * 512 + wave * 128;
        bf16x8 bfr[8][2];
#pragma unroll
        for (int nt = 0; nt < 8; ++nt) {
            size_t cofs = (size_t)(cb + nt * 16 + r) * 64;
            bfr[nt][0] = *(const bf16x8*)(BmatT + cofs + q * 8);
            bfr[nt][1] = *(const bf16x8*)(BmatT + cofs + 32 + q * 8);
        }
#pragma unroll
        for (int mt = 0; mt < 8; ++mt) {
            int e = eb + mt * 16 + r;
            if (e >= n1) e = n1 - 1;
            bf16x8 afr0 = *(const bf16x8*)(outbf + (size_t)e * 64 + q * 8);
            bf16x8 afr1 = *(const bf16x8*)(outbf + (size_t)e * 64 + 32 + q * 8);
            f32x4 acc[8];
#pragma unroll
            for (int nt = 0; nt < 8; ++nt) {
                acc[nt] = __builtin_amdgcn_mfma_f32_16x16x32_bf16(afr0, bfr[nt][0], (f32x4){}, 0, 0, 0);
                acc[nt] = __builtin_amdgcn_mfma_f32_16x16x32_bf16(afr1, bfr[nt][1], acc[nt], 0, 0, 0);
            }
#pragma unroll
            for (int rg = 0; rg < 4; ++rg) {
                int n = eb + mt * 16 + q * 4 + rg;   // C/D: col=lane&15, row=quad*4+reg
                if (n >= n1) continue;
                ushort4 pa, pb;
                pa.x = f32_to_bf16(acc[0][rg]); pa.y = f32_to_bf16(acc[1][rg]);
                pa.z = f32_to_bf16(acc[2][rg]); pa.w = f32_to_bf16(acc[3][rg]);
                pb.x = f32_to_bf16(acc[4][rg]); pb.y = f32_to_bf16(acc[5][rg]);
                pb.z = f32_to_bf16(acc[6][rg]); pb.w = f32_to_bf16(acc[7][rg]);
                uint4 pk = { ((uint32_t)pa.y << 16) | pa.x, ((uint32_t)pa.w << 16) | pa.z,
                             ((uint32_t)pb.y << 16) | pb.x, ((uint32_t)pb.w << 16) | pb.z };
                *(uint4*)(T + (size_t)(n - n0) * TC + cb + 8 * r) = pk;
            }
        }
    } else {
        if (wave != 0) return;               // bias tail: 64 cols only
        int cb = 8192;
        bf16x8 bfr[4][2];
#pragma unroll
        for (int nt = 0; nt < 4; ++nt) {
            size_t cofs = (size_t)(cb + nt * 16 + r) * 64;
            bfr[nt][0] = *(const bf16x8*)(BmatT + cofs + q * 8);
            bfr[nt][1] = *(const bf16x8*)(BmatT + cofs + 32 + q * 8);
        }
#pragma unroll
        for (int mt = 0; mt < 8; ++mt) {
            int e = eb + mt * 16 + r;
            if (e >= n1) e = n1 - 1;
            bf16x8 afr0 = *(const bf16x8*)(outbf + (size_t)e * 64 + q * 8);
            bf16x8 afr1 = *(const bf16x8*)(outbf + (size_t)e * 64 + 32 + q * 8);
            f32x4 acc[4];
#pragma unroll
            for (int nt = 0; nt < 4; ++nt) {
                acc[nt] = __builtin_amdgcn_mfma_f32_16x16x32_bf16(afr0, bfr[nt][0], (f32x4){}, 0, 0, 0);
                acc[nt] = __builtin_amdgcn_mfma_f32_16x16x32_bf16(afr1, bfr[nt][1], acc[nt], 0, 0, 0);
            }
#pragma unroll
            for (int rg = 0; rg < 4; ++rg) {
                int n = eb + mt * 16 + q * 4 + rg;
                if (n >= n1) continue;
                ushort4 pk;
                pk.x = f32_to_bf16(acc[0][rg]);
                pk.y = f32_to_bf16(acc[1][rg]);
                pk.z = f32_to_bf16(acc[2][rg]);
                pk.w = f32_to_bf16(acc[3][rg]);
                *(ushort4*)(T + (size_t)(n - n0) * TC + cb + 4 * r) = pk;
            }
        }
    }
}

// per src-node wave, MFMA: msg[tile of 16 edges][64 o] = h[edges, 0:128] @ T''[n]
// msg stored col-permuted: mem col 4r+nt holds mfma col nt*16+r (16-B f32x4 stores);
// k_agg applies the inverse perm.
__global__ void k_msg(const unsigned short* __restrict__ h, const unsigned short* __restrict__ T,
                      const int* __restrict__ offS, const int* __restrict__ permS,
                      float* __restrict__ msg, int n0, int n1) {
    int wave = threadIdx.x >> 6, lane = threadIdx.x & 63;
    int n = n0 + blockIdx.x * 4 + wave;
    if (n >= n1) return;
    int beg = offS[n], end = offS[n + 1];
    if (beg == end) return;
    int r = lane & 15, q = lane >> 4;
    const unsigned short* Tb = T + (size_t)(n - n0) * TC;
    float bias[4];
#pragma unroll
    for (int nt = 0; nt < 4; ++nt)
        bias[nt] = bfu_to_f(Tb[8192 + nt * 16 + r]);
    for (int j0 = beg; j0 < end; j0 += 16) {
        int jc = j0 + r; if (jc >= end) jc = end - 1;
        int e = permS[jc];
        const unsigned short* he = h + (size_t)e * EHID;
        f32x4 acc[4] = {};
#pragma unroll
        for (int s = 0; s < 4; ++s) {        // K = 128 = 4*32
            bf16x8 afr = *(const bf16x8*)(he + s * 32 + q * 8);
#pragma unroll
            for (int nt = 0; nt < 4; ++nt) {
                bf16x8 bfr = *(const bf16x8*)(Tb + s * 2048 + (nt * 16 + r) * 32 + q * 8);
                acc[nt] = __builtin_amdgcn_mfma_f32_16x16x32_bf16(afr, bfr, acc[nt], 0, 0, 0);
            }
        }
#pragma unroll
        for (int rg = 0; rg < 4; ++rg) {
            int jr = j0 + q * 4 + rg;
            if (jr >= end) continue;
            int er = permS[jr];
            f32x4 pk = { acc[0][rg] + bias[0], acc[1][rg] + bias[1],
                         acc[2][rg] + bias[2], acc[3][rg] + bias[3] };
            *(f32x4*)(msg + (size_t)er * 64 + 4 * r) = pk;
        }
    }
}

// exclusive prefix sum (one block per array; blockIdx.x: 0=S, 1=D)
__global__ void k_scan(const int* __restrict__ cntS, const int* __restrict__ cntD,
                       int* __restrict__ offS, int* __restrict__ offD,
                       int* __restrict__ curS, int* __restrict__ curD, int n, int total) {
    const int* cnt = blockIdx.x ? cntD : cntS;
    int* off = blockIdx.x ? offD : offS;
    int* cur = blockIdx.x ? curD : curS;
    __shared__ int part[256];
    int tid = threadIdx.x;
    int chunk = (n + 255) / 256;
    int c0 = tid * chunk, c1 = c0 + chunk; if (c1 > n) c1 = n; if (c0 > n) c0 = n;
    int s = 0;
    for (int i = c0; i < c1; ++i) s += cnt[i];
    part[tid] = s;
    __syncthreads();
    for (int st = 1; st < 256; st <<= 1) {
        int v = (tid >= st) ? part[tid - st] : 0;
        __syncthreads();
        part[tid] += v;
        __syncthreads();
    }
    int run = tid ? part[tid - 1] : 0;
    for (int i = c0; i < c1; ++i) { off[i] = run; cur[i] = run; run += cnt[i]; }
    if (tid == 0) off[n] = total;
}

__global__ void k_perm(const int* __restrict__ src, const int* __restrict__ dst,
                       int* __restrict__ curS, int* __restrict__ curD,
                       int* __restrict__ permS, int* __restrict__ permD, int n_edges) {
    int e = blockIdx.x * 256 + threadIdx.x;
    if (e >= n_edges) return;
    permS[atomicAdd(&curS[src[e]], 1)] = e;
    permD[atomicAdd(&curD[dst[e]], 1)] = e;
}

// per dst-node wave: out[d] = relu(sum msg + cbias); atomic-free.
// msg cols are stored permuted: lane's stored col l is semantic o=(l&3)*16+(l>>2).
__global__ void k_agg(const float* __restrict__ msg, const int* __restrict__ offD,
                      const int* __restrict__ permD, const float* __restrict__ cbias,
                      float* __restrict__ outb, unsigned short* __restrict__ outbf, int n_nodes) {
    int wave = threadIdx.x >> 6, lane = threadIdx.x & 63;
    int d = blockIdx.x * 4 + wave;
    if (d >= n_nodes) return;
    int o = (lane & 3) * 16 + (lane >> 2);
    float acc = 0.f;
    int end = offD[d + 1];
    for (int j = offD[d]; j < end; ++j)
        acc += msg[(size_t)permD[j] * 64 + lane];
    float v = fmaxf(acc + cbias[o], 0.f);
    outb[(size_t)d * 64 + o] = v;
    outbf[(size_t)d * 64 + o] = f32_to_bf16(v);
}

// grid MUST be 64 blocks (row stride 256 hardcoded)
__global__ void k_bn_stats(const float* __restrict__ out, float* __restrict__ stat, int n_nodes) {
    __shared__ float s1[256], s2[256];
    int tid = threadIdx.x;
    int f = tid & 63, g = tid >> 6;
    float sum = 0.f, ss = 0.f;
    for (int r = blockIdx.x * 4 + g; r < n_nodes; r += 256) {
        float v = out[r * HDIM + f];
        sum += v; ss += v * v;
    }
    s1[tid] = sum; s2[tid] = ss;
    __syncthreads();
    if (tid < 64) {
        float A = s1[tid] + s1[64 + tid] + s1[128 + tid] + s1[192 + tid];
        float B = s2[tid] + s2[64 + tid] + s2[128 + tid] + s2[192 + tid];
        atomicAdd(&stat[tid], A);
        atomicAdd(&stat[64 + tid], B);
    }
}

// bn_final fused in: every thread derives scale/shift from stat (identical arith)
__global__ void k_bn_apply(const float* __restrict__ out, const float* __restrict__ stat,
                           const float* __restrict__ gamma, const float* __restrict__ beta,
                           float* __restrict__ y, int n, int n_nodes) {
    int t = blockIdx.x * 256 + threadIdx.x;
    if (t >= n) return;
    int f = t & 63;
    float mean = stat[f] / n_nodes;
    float var  = stat[64 + f] / n_nodes - mean * mean;   // population var
    float inv  = rsqrtf(var + 1e-5f);
    float scale = gamma[f] * inv;
    float shift = beta[f] - mean * scale;
    y[t] = out[t] * scale + shift;
}

extern "C" void kernel_launch(void* const* d_in, const int* in_sizes, int n_in,
                              void* d_out, int out_size, void* d_ws, size_t ws_size,
                              hipStream_t stream) {
    const float* nf    = (const float*)d_in[0];
    const float* ef    = (const float*)d_in[1];
    const int*   src   = (const int*)d_in[2];
    const int*   dst   = (const int*)d_in[3];
    const float* W0    = (const float*)d_in[4];
    const float* b0    = (const float*)d_in[5];
    const float* We1   = (const float*)d_in[6];
    const float* be1   = (const float*)d_in[7];
    const float* We2   = (const float*)d_in[8];
    const float* be2   = (const float*)d_in[9];
    const float* cbias = (const float*)d_in[10];
    const float* gamma = (const float*)d_in[11];
    const float* beta  = (const float*)d_in[12];
    (void)n_in; (void)out_size;

    int n_nodes = in_sizes[0] / DIN;   // 10000
    int n_edges = in_sizes[2];         // 100000

    char* ws = (char*)d_ws;
    size_t off = 0;
    auto carve = [&](size_t bytes) -> void* {
        void* p = ws + off;
        off = (off + bytes + 255) & ~(size_t)255;
        return p;
    };
    unsigned short* h     = (unsigned short*)carve((size_t)n_edges * EHID * 2);  // 25.6 MB
    float*          msg   = (float*)carve((size_t)n_edges * 64 * 4);             // 25.6 MB
    float*          outb  = (float*)carve((size_t)n_nodes * HDIM * 4);
    unsigned short* outbf = (unsigned short*)carve((size_t)n_nodes * HDIM * 2);
    unsigned short* BmatT = (unsigned short*)carve((size_t)TC * 64 * 2);
    int*            offS  = (int*)carve((size_t)(n_nodes + 1) * 4);
    int*            offD  = (int*)carve((size_t)(n_nodes + 1) * 4);
    int*            curS  = (int*)carve((size_t)n_nodes * 4);
    int*            curD  = (int*)carve((size_t)n_nodes * 4);
    int*            permS = (int*)carve((size_t)n_edges * 4);
    int*            permD = (int*)carve((size_t)n_edges * 4);
    float*          stat  = (float*)carve(128 * 4 + (size_t)2 * n_nodes * 4); // stat + cntS + cntD
    int*            cntS  = (int*)(stat + 128);
    int*            cntD  = cntS + n_nodes;
    unsigned short* T     = (unsigned short*)(ws + off);
    size_t avail = ws_size > off ? ws_size - off : 0;
    long tcap = (long)(avail / ((size_t)TC * 2));   // ws-capacity bound (node rows)
    if (tcap > n_nodes) tcap = n_nodes;
    if (tcap < 64) tcap = 64;
    long tchunk = tcap;   // R7: chunking measured neutral -> single chunk, fewer launches

    hipMemsetAsync(stat, 0, 128 * 4 + (size_t)2 * n_nodes * 4, stream);

    int nbN = (n_nodes + 3) / 4;            // 2500
    int nbE = (n_edges + 63) / 64;          // 1563 (MFMA edge path: 64 edges/block)
    int nbB = (TC * 64 + 255) / 256;        // 2064
    int nbH = (n_edges + 255) / 256;        // 391
    k_pro<<<dim3(nbN + nbE + nbB + nbH), 256, 0, stream>>>(
        nf, W0, b0, outb, outbf, ef, We1, be1, h, We2, be2, BmatT,
        src, dst, cntS, cntD, n_nodes, n_edges, nbN, nbE, nbB);
    k_scan<<<dim3(2), 256, 0, stream>>>(cntS, cntD, offS, offD, curS, curD, n_nodes, n_edges);
    k_perm<<<dim3((n_edges + 255) / 256), 256, 0, stream>>>(src, dst, curS, curD, permS, permD, n_edges);

    for (int step = 0; step < STEPS; ++step) {
        for (long n0 = 0; n0 < n_nodes; n0 += tchunk) {
            long n1 = n0 + tchunk; if (n1 > n_nodes) n1 = n_nodes;
            long cnt = n1 - n0;
            k_T<<<dim3(17, (cnt + 127) / 128), 256, 0, stream>>>(
                outbf, BmatT, T, (int)n0, (int)n1);
            k_msg<<<dim3((cnt + 3) / 4), 256, 0, stream>>>(
                h, T, offS, permS, msg, (int)n0, (int)n1);
        }
        k_agg<<<dim3((n_nodes + 3) / 4), 256, 0, stream>>>(msg, offD, permD, cbias, outb, outbf, n_nodes);
    }

    k_bn_stats<<<dim3(64), 256, 0, stream>>>(outb, stat, n_nodes);
    k_bn_apply<<<dim3((n_nodes * HDIM + 255) / 256), 256, 0, stream>>>(
        outb, stat, gamma, beta, (float*)d_out, n_nodes * HDIM, n_nodes);
}